// Round 12
// baseline (3192.210 us; speedup 1.0000x reference)
//
#include <hip/hip_runtime.h>
#include <hip/hip_bf16.h>

typedef __hip_bfloat16 bf16;
typedef unsigned long long u64;
typedef __attribute__((ext_vector_type(8))) short s8v;
typedef __attribute__((ext_vector_type(4))) short s4v;
typedef __attribute__((ext_vector_type(4))) float f4v;

#define DEV __device__ __forceinline__

DEV float to_f32(float x) { return x; }
DEV float to_f32(bf16 x) { return __bfloat162float(x); }
DEV void store_c(float* p, float v) { *p = v; }
DEV void store_c(bf16* p, float v) { *p = __float2bfloat16(v); }
DEV float sigmf(float x) { return 1.f / (1.f + __expf(-x)); }
DEV short f2bs(float x) { bf16 h = __float2bfloat16(x); return *(short*)&h; }

// ---------------- fused f32->bf16 conversion of all 5 weight blocks ----------------
__global__ void cvt_all(const float* __restrict__ s0, bf16* __restrict__ d0,   // 60000
                        const float* __restrict__ s1, bf16* __restrict__ d1,   // 480000
                        const float* __restrict__ s2, bf16* __restrict__ d2,   // 120000
                        const float* __restrict__ s3, bf16* __restrict__ d3,   // 240000
                        const float* __restrict__ s4, bf16* __restrict__ d4) { // 80000
  int i = blockIdx.x * blockDim.x + threadIdx.x;
  if (i < 60000) d0[i] = __float2bfloat16(s0[i]);
  i -= 60000;
  if (i >= 0 && i < 480000) d1[i] = __float2bfloat16(s1[i]);
  i -= 480000;
  if (i >= 0 && i < 120000) d2[i] = __float2bfloat16(s2[i]);
  i -= 120000;
  if (i >= 0 && i < 240000) d3[i] = __float2bfloat16(s3[i]);
  i -= 240000;
  if (i >= 0 && i < 80000) d4[i] = __float2bfloat16(s4[i]);
}

// ---------------- MFMA GEMM 128x128 tile: C[M,N] = A[M,K]bf16 @ W[N,K]bf16^T (+bias) ------
// 4 waves (2x2), each wave 64x64 out = 4x4 frags of 16x16; 64 MFMA per K32-step per block.
// Staging: 256 threads, each loads 32B (16 shorts) of one A-row and one W-row half.
// GATHER mode: A[m][k] = bf16(embed[idx[m]][k]) staged on the fly.
template <typename TC, bool HAS_BIAS, bool GATHER>
__global__ __launch_bounds__(256) void gemm_mfma(
    const bf16* __restrict__ A, const int* __restrict__ idx,
    const float* __restrict__ embedp, const bf16* __restrict__ W,
    const float* __restrict__ bias, TC* __restrict__ C,
    int M, int N, int K) {
  __shared__ short Als[128 * 32];
  __shared__ short Wls[128 * 32];
  const int tid = threadIdx.x;
  const int m0 = blockIdx.x * 128;
  const int n0 = blockIdx.y * 128;
  const int lane = tid & 63;
  const int wv = tid >> 6;
  const int wm = wv >> 1, wn = wv & 1;
  const int lq = lane >> 4, lr = lane & 15;
  const int row2 = tid >> 1;        // staging row 0..127 (for both A and W)
  const int half = tid & 1;         // k-half: shorts [half*16, half*16+16)

  int vrow = 0;
  if (GATHER) vrow = idx[m0 + row2];
  const int nrow = n0 + row2;

  f4v acc[4][4];
#pragma unroll
  for (int i = 0; i < 4; ++i)
#pragma unroll
    for (int j = 0; j < 4; ++j) acc[i][j] = (f4v){0.f, 0.f, 0.f, 0.f};

  for (int k0 = 0; k0 < K; k0 += 32) {
    // ---- stage A: thread covers shorts [half*16, half*16+16) of row row2 ----
#pragma unroll
    for (int ss = 0; ss < 4; ++ss) {
      int kk = k0 + half * 16 + ss * 4;
      short* dst = &Als[row2 * 32 + half * 16 + ss * 4];
      if (GATHER) {
        if (kk + 4 <= K) {
          float4 a4 = *(const float4*)(embedp + (size_t)vrow * 100 + kk);
          s4v v = {f2bs(a4.x), f2bs(a4.y), f2bs(a4.z), f2bs(a4.w)};
          *(s4v*)dst = v;
        } else {
#pragma unroll
          for (int j = 0; j < 4; ++j)
            dst[j] = (kk + j < K) ? f2bs(embedp[(size_t)vrow * 100 + kk + j]) : (short)0;
        }
      } else {
        const short* src = (const short*)(A + (size_t)(m0 + row2) * K + kk);
        if (kk + 4 <= K) {
          *(s4v*)dst = *(const s4v*)src;
        } else {
#pragma unroll
          for (int j = 0; j < 4; ++j) dst[j] = (kk + j < K) ? src[j] : (short)0;
        }
      }
    }
    // ---- stage W (guard n < N) ----
#pragma unroll
    for (int ss = 0; ss < 4; ++ss) {
      int kk = k0 + half * 16 + ss * 4;
      short* dst = &Wls[row2 * 32 + half * 16 + ss * 4];
      if (nrow < N) {
        const short* src = (const short*)(W + (size_t)nrow * K + kk);
        if (kk + 4 <= K) {
          *(s4v*)dst = *(const s4v*)src;
        } else {
#pragma unroll
          for (int j = 0; j < 4; ++j) dst[j] = (kk + j < K) ? src[j] : (short)0;
        }
      } else {
        *(s4v*)dst = (s4v){0, 0, 0, 0};
      }
    }
    __syncthreads();
    s8v af[4], bfr[4];
#pragma unroll
    for (int mi = 0; mi < 4; ++mi) {
      int r = wm * 64 + mi * 16 + lr;
      af[mi] = *(const s8v*)&Als[r * 32 + lq * 8];
    }
#pragma unroll
    for (int ni = 0; ni < 4; ++ni) {
      int r = wn * 64 + ni * 16 + lr;
      bfr[ni] = *(const s8v*)&Wls[r * 32 + lq * 8];
    }
#pragma unroll
    for (int mi = 0; mi < 4; ++mi)
#pragma unroll
      for (int ni = 0; ni < 4; ++ni)
        acc[mi][ni] = __builtin_amdgcn_mfma_f32_16x16x32_bf16(af[mi], bfr[ni], acc[mi][ni], 0, 0, 0);
    __syncthreads();
  }
#pragma unroll
  for (int mi = 0; mi < 4; ++mi) {
#pragma unroll
    for (int ni = 0; ni < 4; ++ni) {
      int n = n0 + wn * 64 + ni * 16 + lr;
      if (n >= N) continue;
      float bv = HAS_BIAS ? bias[n] : 0.f;
#pragma unroll
      for (int r = 0; r < 4; ++r) {
        int m = m0 + wm * 64 + mi * 16 + lq * 4 + r;
        store_c(&C[(size_t)m * N + n], acc[mi][ni][r] + bv);
      }
    }
  }
}

// ---------------- GRU scan H=100: 2 gates/thread (measured-best shape), dual-input ---------
// grid (B, NY): y&1 = dir; y>>1 selects (xw0,out0,T0) vs (xw1,out1,T1).
// 192 threads: tid<150 computes gates (2t, 2t+1) with 200 register weights; tid<100 updates.
template <typename TO>
__global__ __launch_bounds__(192) void gru_scan100_dual(
    const bf16* __restrict__ xw0, const bf16* __restrict__ xw1,
    const float* __restrict__ wh,  // [2][300][100]
    const float* __restrict__ bh,  // [2][300]
    TO* __restrict__ out0, TO* __restrict__ out1,
    int T0, int T1) {
  const int b = blockIdx.x;
  const int y = blockIdx.y;
  const int which = y >> 1, dir = y & 1;
  const bf16* xw = which ? xw1 : xw0;
  TO* out = which ? out1 : out0;
  const int T = which ? T1 : T0;
  __shared__ float h_s[100];
  __shared__ float g_s[300];
  const int tid = threadIdx.x;
  float w0[100], w1[100];
  float bias0 = 0.f, bias1 = 0.f;
  if (tid < 150) {
    const float* wr0 = wh + (size_t)dir * 30000 + (size_t)(2 * tid) * 100;
#pragma unroll
    for (int c = 0; c < 25; ++c) {
      float4 v = *(const float4*)(wr0 + 4 * c);
      w0[4 * c] = v.x; w0[4 * c + 1] = v.y; w0[4 * c + 2] = v.z; w0[4 * c + 3] = v.w;
      float4 u = *(const float4*)(wr0 + 100 + 4 * c);
      w1[4 * c] = u.x; w1[4 * c + 1] = u.y; w1[4 * c + 2] = u.z; w1[4 * c + 3] = u.w;
    }
    bias0 = bh[dir * 300 + 2 * tid];
    bias1 = bh[dir * 300 + 2 * tid + 1];
  }
  if (tid < 100) h_s[tid] = 0.f;
  float pxr = 0.f, pxz = 0.f, pxn = 0.f;
  if (tid < 100) {
    int t0 = dir ? (T - 1) : 0;
    size_t base = ((size_t)b * T + t0) * 600 + dir * 300;
    pxr = to_f32(xw[base + tid]);
    pxz = to_f32(xw[base + 100 + tid]);
    pxn = to_f32(xw[base + 200 + tid]);
  }
  __syncthreads();
  for (int step = 0; step < T; ++step) {
    int t = dir ? (T - 1 - step) : step;
    if (tid < 150) {
      float a0 = bias0, a1 = 0.f, a2 = 0.f, a3 = 0.f;
      float b0 = bias1, b1 = 0.f, b2 = 0.f, b3 = 0.f;
#pragma unroll
      for (int c = 0; c < 25; ++c) {
        float4 h4 = *(const float4*)(&h_s[4 * c]);
        a0 += w0[4 * c] * h4.x; a1 += w0[4 * c + 1] * h4.y;
        a2 += w0[4 * c + 2] * h4.z; a3 += w0[4 * c + 3] * h4.w;
        b0 += w1[4 * c] * h4.x; b1 += w1[4 * c + 1] * h4.y;
        b2 += w1[4 * c + 2] * h4.z; b3 += w1[4 * c + 3] * h4.w;
      }
      g_s[2 * tid] = (a0 + a1) + (a2 + a3);
      g_s[2 * tid + 1] = (b0 + b1) + (b2 + b3);
    }
    __syncthreads();
    if (tid < 100) {
      float rr = sigmf(pxr + g_s[tid]);
      float zz = sigmf(pxz + g_s[100 + tid]);
      float nn = tanhf(pxn + rr * g_s[200 + tid]);
      float hn = (1.f - zz) * nn + zz * h_s[tid];
      h_s[tid] = hn;
      store_c(&out[((size_t)b * T + t) * 200 + dir * 100 + tid], hn);
      if (step + 1 < T) {
        int tn = dir ? (T - 2 - step) : (step + 1);
        size_t basen = ((size_t)b * T + tn) * 600 + dir * 300;
        pxr = to_f32(xw[basen + tid]);
        pxz = to_f32(xw[basen + 100 + tid]);
        pxn = to_f32(xw[basen + 200 + tid]);
      }
    }
    __syncthreads();
  }
}

// ---------------- encoder GRU scan H=400: tagged exchange (structural floor shape) ---------
__global__ __launch_bounds__(640) void gru_scan_enc_tag(
    const bf16* __restrict__ xw,   // [B,T,1200]
    const float* __restrict__ wh,  // [1200,400] raw
    const float* __restrict__ bh,  // [1200]
    bf16* __restrict__ out,        // [B,T,400]
    u64* __restrict__ hx,          // [B,2,400] {value,tag} (pre-zeroed EVERY call)
    int T) {
  const int b = blockIdx.x, s = blockIdx.y;
  __shared__ float h_s[400];
  __shared__ float g_s[150];
  const int tid = threadIdx.x;
  const int g = tid >> 2, p = tid & 3;
  const bool active = (tid < 600);
  float w[100];
  float bias = 0.f;
  if (active) {
    int i = g % 50, grp = g / 50;
    int gidx = grp * 400 + s * 50 + i;
    const float* wrow = wh + (size_t)gidx * 400 + p * 100;
#pragma unroll
    for (int c = 0; c < 25; ++c) {
      float4 v = *(const float4*)(wrow + 4 * c);
      w[4 * c] = v.x; w[4 * c + 1] = v.y; w[4 * c + 2] = v.z; w[4 * c + 3] = v.w;
    }
    if (p == 0) bias = bh[gidx];
  }
  for (int k = tid; k < 400; k += 640) h_s[k] = 0.f;
  const int myi = s * 50 + tid;
  float pxr = 0.f, pxz = 0.f, pxn = 0.f;
  if (tid < 50) {
    size_t base0 = (size_t)b * T * 1200;
    pxr = to_f32(xw[base0 + myi]);
    pxz = to_f32(xw[base0 + 400 + myi]);
    pxn = to_f32(xw[base0 + 800 + myi]);
  }
  __syncthreads();

  for (int t = 0; t < T; ++t) {
    if (active) {
      const int hb = p * 100;
      float4 hbuf[25];
#pragma unroll
      for (int c = 0; c < 25; ++c) hbuf[c] = *(const float4*)(&h_s[hb + 4 * c]);
      float a0 = bias, a1 = 0.f, a2 = 0.f, a3 = 0.f;
#pragma unroll
      for (int c = 0; c < 25; ++c) {
        a0 += w[4 * c] * hbuf[c].x; a1 += w[4 * c + 1] * hbuf[c].y;
        a2 += w[4 * c + 2] * hbuf[c].z; a3 += w[4 * c + 3] * hbuf[c].w;
      }
      float acc = (a0 + a1) + (a2 + a3);
      acc += __shfl_xor(acc, 1);
      acc += __shfl_xor(acc, 2);
      if (p == 0) g_s[g] = acc;
    }
    __syncthreads();
    const int par = (t + 1) & 1;
    u64* hxp = hx + ((size_t)b * 2 + par) * 400;
    if (tid < 50) {
      float rr = sigmf(pxr + g_s[tid]);
      float zz = sigmf(pxz + g_s[50 + tid]);
      float nn = tanhf(pxn + rr * g_s[100 + tid]);
      float hn = (1.f - zz) * nn + zz * h_s[myi];
      out[((size_t)b * T + t) * 400 + myi] = __float2bfloat16(hn);
      h_s[myi] = hn;
      u64 pack = (u64)__float_as_uint(hn) | ((u64)(unsigned)(t + 1) << 32);
      __hip_atomic_store(&hxp[myi], pack, __ATOMIC_RELAXED, __HIP_MEMORY_SCOPE_AGENT);
      if (t + 1 < T) {
        size_t basen = ((size_t)b * T + (t + 1)) * 1200;
        pxr = to_f32(xw[basen + myi]);
        pxz = to_f32(xw[basen + 400 + myi]);
        pxn = to_f32(xw[basen + 800 + myi]);
      }
    }
    if (tid < 400 && (tid / 50) != s) {
      const u64* src = &hxp[tid];
      u64 v;
      for (;;) {
        v = __hip_atomic_load(src, __ATOMIC_RELAXED, __HIP_MEMORY_SCOPE_AGENT);
        if ((unsigned)(v >> 32) == (unsigned)(t + 1)) break;
        __builtin_amdgcn_s_sleep(1);
      }
      h_s[tid] = __uint_as_float((unsigned)v);
    }
    __syncthreads();
  }
}

// ---------------- attention with fused trilinear terms ----------------
__global__ __launch_bounds__(256) void attn_main(
    const float* __restrict__ h, const float* __restrict__ u,
    const float* __restrict__ w_sim, float* __restrict__ c2q,
    float* __restrict__ smax, int T) {
  const int b = blockIdx.x;
  const int t0 = blockIdx.y * 32;
  __shared__ float u_s[64 * 201];
  __shared__ float w1_s[200], w2_s[200], w3_s[200];
  __shared__ float th_s[32], tu_s[64];
  __shared__ float hw3_s[200];
  __shared__ float Sp[4][64];
  __shared__ float A_s[64];
  const int tid = threadIdx.x;
  for (int i = tid; i < 64 * 200; i += 256) {
    int l = i / 200, d = i - l * 200;
    u_s[l * 201 + d] = u[((size_t)b * 64 + l) * 200 + d];
  }
  if (tid < 200) {
    w1_s[tid] = w_sim[tid];
    w2_s[tid] = w_sim[200 + tid];
    w3_s[tid] = w_sim[400 + tid];
  }
  __syncthreads();
  {
    int r = tid >> 2, sg = tid & 3;
    float p = 0.f;
    for (int j = 0; j < 50; ++j) p += u_s[r * 201 + sg * 50 + j] * w2_s[sg * 50 + j];
    p += __shfl_down(p, 2);
    p += __shfl_down(p, 1);
    if (sg == 0) tu_s[r] = p;
  }
  {
    int r = tid >> 3, sg = tid & 7;
    float p = 0.f;
    const float* hr = h + ((size_t)b * T + t0 + r) * 200 + sg * 25;
    for (int j = 0; j < 25; ++j) p += hr[j] * w1_s[sg * 25 + j];
    p += __shfl_down(p, 4);
    p += __shfl_down(p, 2);
    p += __shfl_down(p, 1);
    if (sg == 0) th_s[r] = p;
  }
  __syncthreads();
  for (int tt = 0; tt < 32; ++tt) {
    int t = t0 + tt;
    if (tid < 200) hw3_s[tid] = h[((size_t)b * T + t) * 200 + tid] * w3_s[tid];
    __syncthreads();
    int l = tid & 63, q = tid >> 6;
    float p = 0.f;
    for (int d = q * 50; d < q * 50 + 50; ++d) p += hw3_s[d] * u_s[l * 201 + d];
    Sp[q][l] = p;
    __syncthreads();
    if (tid < 64) {
      float s = th_s[tt] + tu_s[l] + Sp[0][l] + Sp[1][l] + Sp[2][l] + Sp[3][l];
      float m = s;
      for (int off = 32; off; off >>= 1) m = fmaxf(m, __shfl_xor(m, off));
      float e = __expf(s - m);
      float ssum = e;
      for (int off = 32; off; off >>= 1) ssum += __shfl_xor(ssum, off);
      A_s[l] = e / ssum;
      if (l == 0) smax[b * T + t] = m;
    }
    __syncthreads();
    if (tid < 200) {
      float acc = 0.f;
      for (int l2 = 0; l2 < 64; ++l2) acc += A_s[l2] * u_s[l2 * 201 + tid];
      c2q[((size_t)b * T + t) * 200 + tid] = acc;
    }
    __syncthreads();
  }
}

// ---------------- fused: batt = softmax(smax row); q2c = sum_t batt*h ----------------
__global__ __launch_bounds__(256) void softmax_q2c(
    const float* __restrict__ smaxv, const float* __restrict__ h,
    float* __restrict__ q2c, int T) {
  int b = blockIdx.x;
  int tid = threadIdx.x;
  __shared__ float red[256];
  __shared__ float batt_s[512];
  float m = -1e30f;
  for (int t = tid; t < T; t += 256) m = fmaxf(m, smaxv[b * T + t]);
  red[tid] = m;
  __syncthreads();
  for (int s = 128; s; s >>= 1) {
    if (tid < s) red[tid] = fmaxf(red[tid], red[tid + s]);
    __syncthreads();
  }
  m = red[0];
  __syncthreads();
  float sum = 0.f;
  for (int t = tid; t < T; t += 256) {
    float e = __expf(smaxv[b * T + t] - m);
    batt_s[t] = e;
    sum += e;
  }
  red[tid] = sum;
  __syncthreads();
  for (int s = 128; s; s >>= 1) {
    if (tid < s) red[tid] += red[tid + s];
    __syncthreads();
  }
  float inv = 1.f / red[0];
  __syncthreads();
  if (tid < 200) {
    float acc = 0.f;
    for (int t = 0; t < T; ++t) acc += batt_s[t] * h[((size_t)b * T + t) * 200 + tid];
    q2c[b * 200 + tid] = acc * inv;
  }
}

// ---------------- G = [h, c2q, h*c2q, h*q2c] (bf16) ----------------
__global__ void build_G(const float* __restrict__ h, const float* __restrict__ c2q,
                        const float* __restrict__ q2c, bf16* __restrict__ G, int T) {
  size_t i = (size_t)blockIdx.x * blockDim.x + threadIdx.x;
  if (i >= (size_t)32 * T * 200) return;
  size_t row = i / 200;
  int d = (int)(i - row * 200);
  int b = (int)(row / T);
  float hv = h[i];
  float cv = c2q[i];
  float qv = q2c[b * 200 + d];
  bf16* g = G + row * 800;
  g[d] = __float2bfloat16(hv);
  g[200 + d] = __float2bfloat16(cv);
  g[400 + d] = __float2bfloat16(hv * cv);
  g[600 + d] = __float2bfloat16(hv * qv);
}

// ---------------- decoder (batch-uniform since dec_in == 0): d2[2][200] ----------------
__global__ __launch_bounds__(512) void decoder_small(
    const float* __restrict__ dwh, const float* __restrict__ dbi,
    const float* __restrict__ dbh, const float* __restrict__ w2,
    float* __restrict__ d2out) {
  __shared__ float hid[400];
  __shared__ float hid2[400];
  __shared__ float gh[1200];
  const int tid = threadIdx.x;
  if (tid < 400) {
    float r = sigmf(dbi[tid] + dbh[tid]);
    float z = sigmf(dbi[400 + tid] + dbh[400 + tid]);
    float n = tanhf(dbi[800 + tid] + r * dbh[800 + tid]);
    hid[tid] = (1.f - z) * n;
  }
  __syncthreads();
  if (tid < 200) {
    float a = 0.f;
    for (int k = 0; k < 400; ++k) a += w2[(size_t)tid * 400 + k] * hid[k];
    d2out[tid] = a;
  }
  for (int j = tid; j < 1200; j += 512) {
    float a = dbh[j];
    for (int k = 0; k < 400; ++k) a += dwh[(size_t)j * 400 + k] * hid[k];
    gh[j] = a;
  }
  __syncthreads();
  if (tid < 400) {
    float r = sigmf(dbi[tid] + gh[tid]);
    float z = sigmf(dbi[400 + tid] + gh[400 + tid]);
    float n = tanhf(dbi[800 + tid] + r * gh[800 + tid]);
    hid2[tid] = (1.f - z) * n + z * hid[tid];
  }
  __syncthreads();
  if (tid < 200) {
    float a = 0.f;
    for (int k = 0; k < 400; ++k) a += w2[(size_t)tid * 400 + k] * hid2[k];
    d2out[200 + tid] = a;
  }
}

// ---------------- fused logits + log_softmax: one block per batch ----------------
__global__ __launch_bounds__(512) void logits_lsm(
    const float* __restrict__ encw1, const float* __restrict__ d2,
    const float* __restrict__ vt, float* __restrict__ outp, int T) {
  int b = blockIdx.x;
  __shared__ float lg[2][512];
  __shared__ float red[512];
  const int tid = threadIdx.x;
  const int wave = tid >> 6, lane = tid & 63;
  for (int r = wave; r < T; r += 8) {
    const float* e = encw1 + ((size_t)b * T + r) * 200;
    float s0 = 0.f, s1 = 0.f;
    for (int p = lane; p < 200; p += 64) {
      float ev = e[p], v = vt[p];
      s0 += tanhf(ev + d2[p]) * v;
      s1 += tanhf(ev + d2[200 + p]) * v;
    }
    for (int off = 32; off; off >>= 1) {
      s0 += __shfl_down(s0, off);
      s1 += __shfl_down(s1, off);
    }
    if (lane == 0) { lg[0][r] = s0; lg[1][r] = s1; }
  }
  __syncthreads();
  for (int it = 0; it < 2; ++it) {
    red[tid] = lg[it][tid];
    __syncthreads();
    for (int s = 256; s; s >>= 1) {
      if (tid < s) red[tid] = fmaxf(red[tid], red[tid + s]);
      __syncthreads();
    }
    float m = red[0];
    __syncthreads();
    red[tid] = __expf(lg[it][tid] - m);
    __syncthreads();
    for (int s = 256; s; s >>= 1) {
      if (tid < s) red[tid] += red[tid + s];
      __syncthreads();
    }
    float lse = m + __logf(red[0]);
    __syncthreads();
    outp[((size_t)b * 2 + it) * T + tid] = lg[it][tid] - lse;
  }
}

extern "C" void kernel_launch(void* const* d_in, const int* in_sizes, int n_in,
                              void* d_out, int out_size, void* d_ws, size_t ws_size,
                              hipStream_t stream) {
  (void)in_sizes; (void)n_in; (void)out_size; (void)ws_size;
  const int B = 32, T = 512, L = 64;
  const int BT = B * T;
  const int BL = B * L;

  const int* x_word = (const int*)d_in[0];
  const int* x_query = (const int*)d_in[1];
  const float* embed = (const float*)d_in[2];
  const float* ctx_wi = (const float*)d_in[3];
  const float* ctx_wh = (const float*)d_in[4];
  const float* ctx_bi = (const float*)d_in[5];
  const float* ctx_bh = (const float*)d_in[6];
  const float* mod0_wi = (const float*)d_in[7];
  const float* mod0_wh = (const float*)d_in[8];
  const float* mod0_bi = (const float*)d_in[9];
  const float* mod0_bh = (const float*)d_in[10];
  const float* mod1_wi = (const float*)d_in[11];
  const float* mod1_wh = (const float*)d_in[12];
  const float* mod1_bi = (const float*)d_in[13];
  const float* mod1_bh = (const float*)d_in[14];
  const float* w_sim = (const float*)d_in[15];
  const float* enc_wi = (const float*)d_in[16];
  const float* enc_wh = (const float*)d_in[17];
  const float* enc_bi = (const float*)d_in[18];
  const float* enc_bh = (const float*)d_in[19];
  const float* dec_wh = (const float*)d_in[21];
  const float* dec_bi = (const float*)d_in[22];
  const float* dec_bh = (const float*)d_in[23];
  const float* w1 = (const float*)d_in[24];
  const float* w2 = (const float*)d_in[25];
  const float* vt = (const float*)d_in[26];
  float* out_f = (float*)d_out;

  char* ws = (char*)d_ws;
  size_t off = 0;
  auto alloc = [&](size_t bytes) -> void* {
    void* p = ws + off;
    off += (bytes + 255) & ~(size_t)255;
    return p;
  };
  u64* hx = (u64*)alloc((size_t)B * 2 * 400 * 8);
  bf16* ctx_wibf = (bf16*)alloc((size_t)60000 * 2);
  bf16* mod0_wibf = (bf16*)alloc((size_t)480000 * 2);
  bf16* mod1_wibf = (bf16*)alloc((size_t)120000 * 2);
  bf16* enc_wibf = (bf16*)alloc((size_t)240000 * 2);
  bf16* w1bf = (bf16*)alloc((size_t)80000 * 2);
  char* RA = (char*)alloc((size_t)BT * 1200 * 2);  // xw [BT,600] or xwe [BT,1200]
  bf16* xwFB = (bf16*)RA;
  bf16* xwe = (bf16*)RA;
  bf16* xwq = (bf16*)alloc((size_t)BL * 600 * 2);
  char* RB = (char*)alloc((size_t)BT * 800 * 2);
  bf16* G = (bf16*)RB;
  bf16* enc_outbf = (bf16*)RB;
  char* RC = (char*)alloc((size_t)2 * BT * 200 * 4);
  float* h_cat = (float*)RC;
  float* c2q = (float*)(RC + (size_t)BT * 200 * 4);
  bf16* M0bf = (bf16*)c2q;
  bf16* Mxbf = (bf16*)h_cat;
  float* encw1 = c2q;
  float* u_cat = (float*)alloc((size_t)BL * 200 * 4);
  float* smaxb = (float*)alloc((size_t)BT * 4);
  float* q2cb = (float*)alloc((size_t)B * 200 * 4);
  float* d2 = (float*)alloc((size_t)400 * 4);

  // ---- 0. zero hx EVERY call (stale tags would satisfy polls across graph replays) ----
  hipMemsetAsync(hx, 0, (size_t)B * 2 * 400 * 8, stream);

  // ---- 1. weight conversions (fused) ----
  cvt_all<<<(980000 + 255) / 256, 256, 0, stream>>>(ctx_wi, ctx_wibf, mod0_wi, mod0_wibf,
                                                    mod1_wi, mod1_wibf, enc_wi, enc_wibf,
                                                    w1, w1bf);

  // ---- 2. ctx input projections, embedding gather FUSED into A-staging (128x128 tile) ----
  gemm_mfma<bf16, true, true><<<dim3(BT / 128, 5), 256, 0, stream>>>(
      nullptr, x_word, embed, ctx_wibf, ctx_bi, xwFB, BT, 600, 100);
  gemm_mfma<bf16, true, true><<<dim3(BL / 128, 5), 256, 0, stream>>>(
      nullptr, x_query, embed, ctx_wibf, ctx_bi, xwq, BL, 600, 100);

  // ---- 3. ctx scans: word (T=512) and query (L=64) merged into one launch ----
  gru_scan100_dual<float><<<dim3(B, 4), 192, 0, stream>>>(
      xwFB, xwq, ctx_wh, ctx_bh, h_cat, u_cat, T, L);

  // ---- 4. attention ----
  attn_main<<<dim3(B, T / 32), 256, 0, stream>>>(h_cat, u_cat, w_sim, c2q, smaxb, T);
  softmax_q2c<<<B, 256, 0, stream>>>(smaxb, h_cat, q2cb, T);
  build_G<<<(BT * 200 + 255) / 256, 256, 0, stream>>>(h_cat, c2q, q2cb, G, T);

  // ---- 5. mod0 ----
  gemm_mfma<bf16, true, false><<<dim3(BT / 128, 5), 256, 0, stream>>>(
      G, nullptr, nullptr, mod0_wibf, mod0_bi, xwFB, BT, 600, 800);
  gru_scan100_dual<bf16><<<dim3(B, 2), 192, 0, stream>>>(
      xwFB, nullptr, mod0_wh, mod0_bh, M0bf, nullptr, T, T);

  // ---- 6. mod1 ----
  gemm_mfma<bf16, true, false><<<dim3(BT / 128, 5), 256, 0, stream>>>(
      M0bf, nullptr, nullptr, mod1_wibf, mod1_bi, xwFB, BT, 600, 200);
  gru_scan100_dual<bf16><<<dim3(B, 2), 192, 0, stream>>>(
      xwFB, nullptr, mod1_wh, mod1_bh, Mxbf, nullptr, T, T);

  // ---- 7. encoder ----
  gemm_mfma<bf16, true, false><<<dim3(BT / 128, 10), 256, 0, stream>>>(
      Mxbf, nullptr, nullptr, enc_wibf, enc_bi, xwe, BT, 1200, 200);
  gru_scan_enc_tag<<<dim3(B, 8), 640, 0, stream>>>(xwe, enc_wh, enc_bh, enc_outbf, hx, T);
  gemm_mfma<float, false, false><<<dim3(BT / 128, 2), 256, 0, stream>>>(
      enc_outbf, nullptr, nullptr, w1bf, nullptr, encw1, BT, 200, 400);

  // ---- 8. pointer decoder (fused logits + log_softmax) ----
  decoder_small<<<1, 512, 0, stream>>>(dec_wh, dec_bi, dec_bh, w2, d2);
  logits_lsm<<<B, 512, 0, stream>>>(encw1, d2, vt, out_f, T);
}

// Round 13
// 3184.993 us; speedup vs baseline: 1.0023x; 1.0023x over previous
//
#include <hip/hip_runtime.h>
#include <hip/hip_bf16.h>

typedef __hip_bfloat16 bf16;
typedef unsigned long long u64;
typedef __attribute__((ext_vector_type(8))) short s8v;
typedef __attribute__((ext_vector_type(4))) short s4v;
typedef __attribute__((ext_vector_type(4))) float f4v;

#define DEV __device__ __forceinline__

DEV float to_f32(float x) { return x; }
DEV float to_f32(bf16 x) { return __bfloat162float(x); }
DEV void store_c(float* p, float v) { *p = v; }
DEV void store_c(bf16* p, float v) { *p = __float2bfloat16(v); }
DEV float sigmf(float x) { return 1.f / (1.f + __expf(-x)); }
DEV short f2bs(float x) { bf16 h = __float2bfloat16(x); return *(short*)&h; }

// ---------------- fused f32->bf16 conversion of all 5 weight blocks ----------------
__global__ void cvt_all(const float* __restrict__ s0, bf16* __restrict__ d0,   // 60000
                        const float* __restrict__ s1, bf16* __restrict__ d1,   // 480000
                        const float* __restrict__ s2, bf16* __restrict__ d2,   // 120000
                        const float* __restrict__ s3, bf16* __restrict__ d3,   // 240000
                        const float* __restrict__ s4, bf16* __restrict__ d4) { // 80000
  int i = blockIdx.x * blockDim.x + threadIdx.x;
  if (i < 60000) d0[i] = __float2bfloat16(s0[i]);
  i -= 60000;
  if (i >= 0 && i < 480000) d1[i] = __float2bfloat16(s1[i]);
  i -= 480000;
  if (i >= 0 && i < 120000) d2[i] = __float2bfloat16(s2[i]);
  i -= 120000;
  if (i >= 0 && i < 240000) d3[i] = __float2bfloat16(s3[i]);
  i -= 240000;
  if (i >= 0 && i < 80000) d4[i] = __float2bfloat16(s4[i]);
}

// ---------------- MFMA GEMM 128x128, double-buffered LDS pipeline -------------------------
// Per iteration: issue tile k+1 global loads (reg-staged), MFMA tile k, write regs->LDS
// (other buffer), ONE barrier. Global latency hides under the 64-MFMA compute.
// GATHER mode: A[m][k] = bf16(embed[idx[m]][k]).
template <typename TC, bool HAS_BIAS, bool GATHER>
__global__ __launch_bounds__(256) void gemm_mfma(
    const bf16* __restrict__ A, const int* __restrict__ idx,
    const float* __restrict__ embedp, const bf16* __restrict__ W,
    const float* __restrict__ bias, TC* __restrict__ C,
    int M, int N, int K) {
  __shared__ short Als[2][128 * 32];
  __shared__ short Wls[2][128 * 32];
  const int tid = threadIdx.x;
  const int m0 = blockIdx.x * 128;
  const int n0 = blockIdx.y * 128;
  const int lane = tid & 63;
  const int wv = tid >> 6;
  const int wm = wv >> 1, wn = wv & 1;
  const int lq = lane >> 4, lr = lane & 15;
  const int row2 = tid >> 1;   // staging row 0..127
  const int half = tid & 1;    // k-half: shorts [half*16, half*16+16)

  int vrow = 0;
  if (GATHER) vrow = idx[m0 + row2];
  const int nrow = n0 + row2;

  s4v ra[4], rw[4];
  auto load_regs = [&](int k0) {
#pragma unroll
    for (int ss = 0; ss < 4; ++ss) {
      int kk = k0 + half * 16 + ss * 4;
      if (GATHER) {
        if (kk + 4 <= K) {
          float4 a4 = *(const float4*)(embedp + (size_t)vrow * 100 + kk);
          ra[ss] = (s4v){f2bs(a4.x), f2bs(a4.y), f2bs(a4.z), f2bs(a4.w)};
        } else {
          s4v v = {0, 0, 0, 0};
#pragma unroll
          for (int j = 0; j < 4; ++j)
            if (kk + j < K) v[j] = f2bs(embedp[(size_t)vrow * 100 + kk + j]);
          ra[ss] = v;
        }
      } else {
        const short* src = (const short*)(A + (size_t)(m0 + row2) * K + kk);
        if (kk + 4 <= K) {
          ra[ss] = *(const s4v*)src;
        } else {
          s4v v = {0, 0, 0, 0};
#pragma unroll
          for (int j = 0; j < 4; ++j)
            if (kk + j < K) v[j] = src[j];
          ra[ss] = v;
        }
      }
      if (nrow < N) {
        const short* src = (const short*)(W + (size_t)nrow * K + kk);
        if (kk + 4 <= K) {
          rw[ss] = *(const s4v*)src;
        } else {
          s4v v = {0, 0, 0, 0};
#pragma unroll
          for (int j = 0; j < 4; ++j)
            if (kk + j < K) v[j] = src[j];
          rw[ss] = v;
        }
      } else {
        rw[ss] = (s4v){0, 0, 0, 0};
      }
    }
  };
  auto write_lds = [&](int buf) {
#pragma unroll
    for (int ss = 0; ss < 4; ++ss) {
      *(s4v*)&Als[buf][row2 * 32 + half * 16 + ss * 4] = ra[ss];
      *(s4v*)&Wls[buf][row2 * 32 + half * 16 + ss * 4] = rw[ss];
    }
  };

  f4v acc[4][4];
#pragma unroll
  for (int i = 0; i < 4; ++i)
#pragma unroll
    for (int j = 0; j < 4; ++j) acc[i][j] = (f4v){0.f, 0.f, 0.f, 0.f};

  const int nk = (K + 31) / 32;
  load_regs(0);
  write_lds(0);
  __syncthreads();
  int cur = 0;
  for (int ki = 0; ki < nk; ++ki) {
    if (ki + 1 < nk) load_regs((ki + 1) * 32);  // loads in flight across the MFMAs below
    s8v af[4], bfr[4];
#pragma unroll
    for (int mi = 0; mi < 4; ++mi) {
      int r = wm * 64 + mi * 16 + lr;
      af[mi] = *(const s8v*)&Als[cur][r * 32 + lq * 8];
    }
#pragma unroll
    for (int ni = 0; ni < 4; ++ni) {
      int r = wn * 64 + ni * 16 + lr;
      bfr[ni] = *(const s8v*)&Wls[cur][r * 32 + lq * 8];
    }
#pragma unroll
    for (int mi = 0; mi < 4; ++mi)
#pragma unroll
      for (int ni = 0; ni < 4; ++ni)
        acc[mi][ni] = __builtin_amdgcn_mfma_f32_16x16x32_bf16(af[mi], bfr[ni], acc[mi][ni], 0, 0, 0);
    if (ki + 1 < nk) write_lds(cur ^ 1);  // safe: last reads of buf cur^1 pre-date prior barrier
    __syncthreads();
    cur ^= 1;
  }
#pragma unroll
  for (int mi = 0; mi < 4; ++mi) {
#pragma unroll
    for (int ni = 0; ni < 4; ++ni) {
      int n = n0 + wn * 64 + ni * 16 + lr;
      if (n >= N) continue;
      float bv = HAS_BIAS ? bias[n] : 0.f;
#pragma unroll
      for (int r = 0; r < 4; ++r) {
        int m = m0 + wm * 64 + mi * 16 + lq * 4 + r;
        store_c(&C[(size_t)m * N + n], acc[mi][ni][r] + bv);
      }
    }
  }
}

// ---------------- GRU scan H=100: 2 gates/thread (measured-best shape), dual-input ---------
template <typename TO>
__global__ __launch_bounds__(192) void gru_scan100_dual(
    const bf16* __restrict__ xw0, const bf16* __restrict__ xw1,
    const float* __restrict__ wh,  // [2][300][100]
    const float* __restrict__ bh,  // [2][300]
    TO* __restrict__ out0, TO* __restrict__ out1,
    int T0, int T1) {
  const int b = blockIdx.x;
  const int y = blockIdx.y;
  const int which = y >> 1, dir = y & 1;
  const bf16* xw = which ? xw1 : xw0;
  TO* out = which ? out1 : out0;
  const int T = which ? T1 : T0;
  __shared__ float h_s[100];
  __shared__ float g_s[300];
  const int tid = threadIdx.x;
  float w0[100], w1[100];
  float bias0 = 0.f, bias1 = 0.f;
  if (tid < 150) {
    const float* wr0 = wh + (size_t)dir * 30000 + (size_t)(2 * tid) * 100;
#pragma unroll
    for (int c = 0; c < 25; ++c) {
      float4 v = *(const float4*)(wr0 + 4 * c);
      w0[4 * c] = v.x; w0[4 * c + 1] = v.y; w0[4 * c + 2] = v.z; w0[4 * c + 3] = v.w;
      float4 u = *(const float4*)(wr0 + 100 + 4 * c);
      w1[4 * c] = u.x; w1[4 * c + 1] = u.y; w1[4 * c + 2] = u.z; w1[4 * c + 3] = u.w;
    }
    bias0 = bh[dir * 300 + 2 * tid];
    bias1 = bh[dir * 300 + 2 * tid + 1];
  }
  if (tid < 100) h_s[tid] = 0.f;
  float pxr = 0.f, pxz = 0.f, pxn = 0.f;
  if (tid < 100) {
    int t0 = dir ? (T - 1) : 0;
    size_t base = ((size_t)b * T + t0) * 600 + dir * 300;
    pxr = to_f32(xw[base + tid]);
    pxz = to_f32(xw[base + 100 + tid]);
    pxn = to_f32(xw[base + 200 + tid]);
  }
  __syncthreads();
  for (int step = 0; step < T; ++step) {
    int t = dir ? (T - 1 - step) : step;
    if (tid < 150) {
      float a0 = bias0, a1 = 0.f, a2 = 0.f, a3 = 0.f;
      float b0 = bias1, b1 = 0.f, b2 = 0.f, b3 = 0.f;
#pragma unroll
      for (int c = 0; c < 25; ++c) {
        float4 h4 = *(const float4*)(&h_s[4 * c]);
        a0 += w0[4 * c] * h4.x; a1 += w0[4 * c + 1] * h4.y;
        a2 += w0[4 * c + 2] * h4.z; a3 += w0[4 * c + 3] * h4.w;
        b0 += w1[4 * c] * h4.x; b1 += w1[4 * c + 1] * h4.y;
        b2 += w1[4 * c + 2] * h4.z; b3 += w1[4 * c + 3] * h4.w;
      }
      g_s[2 * tid] = (a0 + a1) + (a2 + a3);
      g_s[2 * tid + 1] = (b0 + b1) + (b2 + b3);
    }
    __syncthreads();
    if (tid < 100) {
      float rr = sigmf(pxr + g_s[tid]);
      float zz = sigmf(pxz + g_s[100 + tid]);
      float nn = tanhf(pxn + rr * g_s[200 + tid]);
      float hn = (1.f - zz) * nn + zz * h_s[tid];
      h_s[tid] = hn;
      store_c(&out[((size_t)b * T + t) * 200 + dir * 100 + tid], hn);
      if (step + 1 < T) {
        int tn = dir ? (T - 2 - step) : (step + 1);
        size_t basen = ((size_t)b * T + tn) * 600 + dir * 300;
        pxr = to_f32(xw[basen + tid]);
        pxz = to_f32(xw[basen + 100 + tid]);
        pxn = to_f32(xw[basen + 200 + tid]);
      }
    }
    __syncthreads();
  }
}

// ---------------- encoder GRU scan H=400: tagged exchange (structural floor shape) ---------
__global__ __launch_bounds__(640) void gru_scan_enc_tag(
    const bf16* __restrict__ xw,   // [B,T,1200]
    const float* __restrict__ wh,  // [1200,400] raw
    const float* __restrict__ bh,  // [1200]
    bf16* __restrict__ out,        // [B,T,400]
    u64* __restrict__ hx,          // [B,2,400] {value,tag} (pre-zeroed EVERY call)
    int T) {
  const int b = blockIdx.x, s = blockIdx.y;
  __shared__ float h_s[400];
  __shared__ float g_s[150];
  const int tid = threadIdx.x;
  const int g = tid >> 2, p = tid & 3;
  const bool active = (tid < 600);
  float w[100];
  float bias = 0.f;
  if (active) {
    int i = g % 50, grp = g / 50;
    int gidx = grp * 400 + s * 50 + i;
    const float* wrow = wh + (size_t)gidx * 400 + p * 100;
#pragma unroll
    for (int c = 0; c < 25; ++c) {
      float4 v = *(const float4*)(wrow + 4 * c);
      w[4 * c] = v.x; w[4 * c + 1] = v.y; w[4 * c + 2] = v.z; w[4 * c + 3] = v.w;
    }
    if (p == 0) bias = bh[gidx];
  }
  for (int k = tid; k < 400; k += 640) h_s[k] = 0.f;
  const int myi = s * 50 + tid;
  float pxr = 0.f, pxz = 0.f, pxn = 0.f;
  if (tid < 50) {
    size_t base0 = (size_t)b * T * 1200;
    pxr = to_f32(xw[base0 + myi]);
    pxz = to_f32(xw[base0 + 400 + myi]);
    pxn = to_f32(xw[base0 + 800 + myi]);
  }
  __syncthreads();

  for (int t = 0; t < T; ++t) {
    if (active) {
      const int hb = p * 100;
      float4 hbuf[25];
#pragma unroll
      for (int c = 0; c < 25; ++c) hbuf[c] = *(const float4*)(&h_s[hb + 4 * c]);
      float a0 = bias, a1 = 0.f, a2 = 0.f, a3 = 0.f;
#pragma unroll
      for (int c = 0; c < 25; ++c) {
        a0 += w[4 * c] * hbuf[c].x; a1 += w[4 * c + 1] * hbuf[c].y;
        a2 += w[4 * c + 2] * hbuf[c].z; a3 += w[4 * c + 3] * hbuf[c].w;
      }
      float acc = (a0 + a1) + (a2 + a3);
      acc += __shfl_xor(acc, 1);
      acc += __shfl_xor(acc, 2);
      if (p == 0) g_s[g] = acc;
    }
    __syncthreads();
    const int par = (t + 1) & 1;
    u64* hxp = hx + ((size_t)b * 2 + par) * 400;
    if (tid < 50) {
      float rr = sigmf(pxr + g_s[tid]);
      float zz = sigmf(pxz + g_s[50 + tid]);
      float nn = tanhf(pxn + rr * g_s[100 + tid]);
      float hn = (1.f - zz) * nn + zz * h_s[myi];
      out[((size_t)b * T + t) * 400 + myi] = __float2bfloat16(hn);
      h_s[myi] = hn;
      u64 pack = (u64)__float_as_uint(hn) | ((u64)(unsigned)(t + 1) << 32);
      __hip_atomic_store(&hxp[myi], pack, __ATOMIC_RELAXED, __HIP_MEMORY_SCOPE_AGENT);
      if (t + 1 < T) {
        size_t basen = ((size_t)b * T + (t + 1)) * 1200;
        pxr = to_f32(xw[basen + myi]);
        pxz = to_f32(xw[basen + 400 + myi]);
        pxn = to_f32(xw[basen + 800 + myi]);
      }
    }
    if (tid < 400 && (tid / 50) != s) {
      const u64* src = &hxp[tid];
      u64 v;
      for (;;) {
        v = __hip_atomic_load(src, __ATOMIC_RELAXED, __HIP_MEMORY_SCOPE_AGENT);
        if ((unsigned)(v >> 32) == (unsigned)(t + 1)) break;
        __builtin_amdgcn_s_sleep(1);
      }
      h_s[tid] = __uint_as_float((unsigned)v);
    }
    __syncthreads();
  }
}

// ---------------- attention with fused trilinear terms ----------------
__global__ __launch_bounds__(256) void attn_main(
    const float* __restrict__ h, const float* __restrict__ u,
    const float* __restrict__ w_sim, float* __restrict__ c2q,
    float* __restrict__ smax, int T) {
  const int b = blockIdx.x;
  const int t0 = blockIdx.y * 32;
  __shared__ float u_s[64 * 201];
  __shared__ float w1_s[200], w2_s[200], w3_s[200];
  __shared__ float th_s[32], tu_s[64];
  __shared__ float hw3_s[200];
  __shared__ float Sp[4][64];
  __shared__ float A_s[64];
  const int tid = threadIdx.x;
  for (int i = tid; i < 64 * 200; i += 256) {
    int l = i / 200, d = i - l * 200;
    u_s[l * 201 + d] = u[((size_t)b * 64 + l) * 200 + d];
  }
  if (tid < 200) {
    w1_s[tid] = w_sim[tid];
    w2_s[tid] = w_sim[200 + tid];
    w3_s[tid] = w_sim[400 + tid];
  }
  __syncthreads();
  {
    int r = tid >> 2, sg = tid & 3;
    float p = 0.f;
    for (int j = 0; j < 50; ++j) p += u_s[r * 201 + sg * 50 + j] * w2_s[sg * 50 + j];
    p += __shfl_down(p, 2);
    p += __shfl_down(p, 1);
    if (sg == 0) tu_s[r] = p;
  }
  {
    int r = tid >> 3, sg = tid & 7;
    float p = 0.f;
    const float* hr = h + ((size_t)b * T + t0 + r) * 200 + sg * 25;
    for (int j = 0; j < 25; ++j) p += hr[j] * w1_s[sg * 25 + j];
    p += __shfl_down(p, 4);
    p += __shfl_down(p, 2);
    p += __shfl_down(p, 1);
    if (sg == 0) th_s[r] = p;
  }
  __syncthreads();
  for (int tt = 0; tt < 32; ++tt) {
    int t = t0 + tt;
    if (tid < 200) hw3_s[tid] = h[((size_t)b * T + t) * 200 + tid] * w3_s[tid];
    __syncthreads();
    int l = tid & 63, q = tid >> 6;
    float p = 0.f;
    for (int d = q * 50; d < q * 50 + 50; ++d) p += hw3_s[d] * u_s[l * 201 + d];
    Sp[q][l] = p;
    __syncthreads();
    if (tid < 64) {
      float s = th_s[tt] + tu_s[l] + Sp[0][l] + Sp[1][l] + Sp[2][l] + Sp[3][l];
      float m = s;
      for (int off = 32; off; off >>= 1) m = fmaxf(m, __shfl_xor(m, off));
      float e = __expf(s - m);
      float ssum = e;
      for (int off = 32; off; off >>= 1) ssum += __shfl_xor(ssum, off);
      A_s[l] = e / ssum;
      if (l == 0) smax[b * T + t] = m;
    }
    __syncthreads();
    if (tid < 200) {
      float acc = 0.f;
      for (int l2 = 0; l2 < 64; ++l2) acc += A_s[l2] * u_s[l2 * 201 + tid];
      c2q[((size_t)b * T + t) * 200 + tid] = acc;
    }
    __syncthreads();
  }
}

// ---------------- fused: batt = softmax(smax row); q2c = sum_t batt*h ----------------
__global__ __launch_bounds__(256) void softmax_q2c(
    const float* __restrict__ smaxv, const float* __restrict__ h,
    float* __restrict__ q2c, int T) {
  int b = blockIdx.x;
  int tid = threadIdx.x;
  __shared__ float red[256];
  __shared__ float batt_s[512];
  float m = -1e30f;
  for (int t = tid; t < T; t += 256) m = fmaxf(m, smaxv[b * T + t]);
  red[tid] = m;
  __syncthreads();
  for (int s = 128; s; s >>= 1) {
    if (tid < s) red[tid] = fmaxf(red[tid], red[tid + s]);
    __syncthreads();
  }
  m = red[0];
  __syncthreads();
  float sum = 0.f;
  for (int t = tid; t < T; t += 256) {
    float e = __expf(smaxv[b * T + t] - m);
    batt_s[t] = e;
    sum += e;
  }
  red[tid] = sum;
  __syncthreads();
  for (int s = 128; s; s >>= 1) {
    if (tid < s) red[tid] += red[tid + s];
    __syncthreads();
  }
  float inv = 1.f / red[0];
  __syncthreads();
  if (tid < 200) {
    float acc = 0.f;
    for (int t = 0; t < T; ++t) acc += batt_s[t] * h[((size_t)b * T + t) * 200 + tid];
    q2c[b * 200 + tid] = acc * inv;
  }
}

// ---------------- G = [h, c2q, h*c2q, h*q2c] (bf16) ----------------
__global__ void build_G(const float* __restrict__ h, const float* __restrict__ c2q,
                        const float* __restrict__ q2c, bf16* __restrict__ G, int T) {
  size_t i = (size_t)blockIdx.x * blockDim.x + threadIdx.x;
  if (i >= (size_t)32 * T * 200) return;
  size_t row = i / 200;
  int d = (int)(i - row * 200);
  int b = (int)(row / T);
  float hv = h[i];
  float cv = c2q[i];
  float qv = q2c[b * 200 + d];
  bf16* g = G + row * 800;
  g[d] = __float2bfloat16(hv);
  g[200 + d] = __float2bfloat16(cv);
  g[400 + d] = __float2bfloat16(hv * cv);
  g[600 + d] = __float2bfloat16(hv * qv);
}

// ---------------- decoder (batch-uniform since dec_in == 0): d2[2][200] ----------------
__global__ __launch_bounds__(512) void decoder_small(
    const float* __restrict__ dwh, const float* __restrict__ dbi,
    const float* __restrict__ dbh, const float* __restrict__ w2,
    float* __restrict__ d2out) {
  __shared__ float hid[400];
  __shared__ float hid2[400];
  __shared__ float gh[1200];
  const int tid = threadIdx.x;
  if (tid < 400) {
    float r = sigmf(dbi[tid] + dbh[tid]);
    float z = sigmf(dbi[400 + tid] + dbh[400 + tid]);
    float n = tanhf(dbi[800 + tid] + r * dbh[800 + tid]);
    hid[tid] = (1.f - z) * n;
  }
  __syncthreads();
  if (tid < 200) {
    float a = 0.f;
    for (int k = 0; k < 400; ++k) a += w2[(size_t)tid * 400 + k] * hid[k];
    d2out[tid] = a;
  }
  for (int j = tid; j < 1200; j += 512) {
    float a = dbh[j];
    for (int k = 0; k < 400; ++k) a += dwh[(size_t)j * 400 + k] * hid[k];
    gh[j] = a;
  }
  __syncthreads();
  if (tid < 400) {
    float r = sigmf(dbi[tid] + gh[tid]);
    float z = sigmf(dbi[400 + tid] + gh[400 + tid]);
    float n = tanhf(dbi[800 + tid] + r * gh[800 + tid]);
    hid2[tid] = (1.f - z) * n + z * hid[tid];
  }
  __syncthreads();
  if (tid < 200) {
    float a = 0.f;
    for (int k = 0; k < 400; ++k) a += w2[(size_t)tid * 400 + k] * hid2[k];
    d2out[200 + tid] = a;
  }
}

// ---------------- fused logits + log_softmax: one block per batch ----------------
__global__ __launch_bounds__(512) void logits_lsm(
    const float* __restrict__ encw1, const float* __restrict__ d2,
    const float* __restrict__ vt, float* __restrict__ outp, int T) {
  int b = blockIdx.x;
  __shared__ float lg[2][512];
  __shared__ float red[512];
  const int tid = threadIdx.x;
  const int wave = tid >> 6, lane = tid & 63;
  for (int r = wave; r < T; r += 8) {
    const float* e = encw1 + ((size_t)b * T + r) * 200;
    float s0 = 0.f, s1 = 0.f;
    for (int p = lane; p < 200; p += 64) {
      float ev = e[p], v = vt[p];
      s0 += tanhf(ev + d2[p]) * v;
      s1 += tanhf(ev + d2[200 + p]) * v;
    }
    for (int off = 32; off; off >>= 1) {
      s0 += __shfl_down(s0, off);
      s1 += __shfl_down(s1, off);
    }
    if (lane == 0) { lg[0][r] = s0; lg[1][r] = s1; }
  }
  __syncthreads();
  for (int it = 0; it < 2; ++it) {
    red[tid] = lg[it][tid];
    __syncthreads();
    for (int s = 256; s; s >>= 1) {
      if (tid < s) red[tid] = fmaxf(red[tid], red[tid + s]);
      __syncthreads();
    }
    float m = red[0];
    __syncthreads();
    red[tid] = __expf(lg[it][tid] - m);
    __syncthreads();
    for (int s = 256; s; s >>= 1) {
      if (tid < s) red[tid] += red[tid + s];
      __syncthreads();
    }
    float lse = m + __logf(red[0]);
    __syncthreads();
    outp[((size_t)b * 2 + it) * T + tid] = lg[it][tid] - lse;
  }
}

extern "C" void kernel_launch(void* const* d_in, const int* in_sizes, int n_in,
                              void* d_out, int out_size, void* d_ws, size_t ws_size,
                              hipStream_t stream) {
  (void)in_sizes; (void)n_in; (void)out_size; (void)ws_size;
  const int B = 32, T = 512, L = 64;
  const int BT = B * T;
  const int BL = B * L;

  const int* x_word = (const int*)d_in[0];
  const int* x_query = (const int*)d_in[1];
  const float* embed = (const float*)d_in[2];
  const float* ctx_wi = (const float*)d_in[3];
  const float* ctx_wh = (const float*)d_in[4];
  const float* ctx_bi = (const float*)d_in[5];
  const float* ctx_bh = (const float*)d_in[6];
  const float* mod0_wi = (const float*)d_in[7];
  const float* mod0_wh = (const float*)d_in[8];
  const float* mod0_bi = (const float*)d_in[9];
  const float* mod0_bh = (const float*)d_in[10];
  const float* mod1_wi = (const float*)d_in[11];
  const float* mod1_wh = (const float*)d_in[12];
  const float* mod1_bi = (const float*)d_in[13];
  const float* mod1_bh = (const float*)d_in[14];
  const float* w_sim = (const float*)d_in[15];
  const float* enc_wi = (const float*)d_in[16];
  const float* enc_wh = (const float*)d_in[17];
  const float* enc_bi = (const float*)d_in[18];
  const float* enc_bh = (const float*)d_in[19];
  const float* dec_wh = (const float*)d_in[21];
  const float* dec_bi = (const float*)d_in[22];
  const float* dec_bh = (const float*)d_in[23];
  const float* w1 = (const float*)d_in[24];
  const float* w2 = (const float*)d_in[25];
  const float* vt = (const float*)d_in[26];
  float* out_f = (float*)d_out;

  char* ws = (char*)d_ws;
  size_t off = 0;
  auto alloc = [&](size_t bytes) -> void* {
    void* p = ws + off;
    off += (bytes + 255) & ~(size_t)255;
    return p;
  };
  u64* hx = (u64*)alloc((size_t)B * 2 * 400 * 8);
  bf16* ctx_wibf = (bf16*)alloc((size_t)60000 * 2);
  bf16* mod0_wibf = (bf16*)alloc((size_t)480000 * 2);
  bf16* mod1_wibf = (bf16*)alloc((size_t)120000 * 2);
  bf16* enc_wibf = (bf16*)alloc((size_t)240000 * 2);
  bf16* w1bf = (bf16*)alloc((size_t)80000 * 2);
  char* RA = (char*)alloc((size_t)BT * 1200 * 2);  // xw [BT,600] or xwe [BT,1200]
  bf16* xwFB = (bf16*)RA;
  bf16* xwe = (bf16*)RA;
  bf16* xwq = (bf16*)alloc((size_t)BL * 600 * 2);
  char* RB = (char*)alloc((size_t)BT * 800 * 2);
  bf16* G = (bf16*)RB;
  bf16* enc_outbf = (bf16*)RB;
  char* RC = (char*)alloc((size_t)2 * BT * 200 * 4);
  float* h_cat = (float*)RC;
  float* c2q = (float*)(RC + (size_t)BT * 200 * 4);
  bf16* M0bf = (bf16*)c2q;
  bf16* Mxbf = (bf16*)h_cat;
  float* encw1 = c2q;
  float* u_cat = (float*)alloc((size_t)BL * 200 * 4);
  float* smaxb = (float*)alloc((size_t)BT * 4);
  float* q2cb = (float*)alloc((size_t)B * 200 * 4);
  float* d2 = (float*)alloc((size_t)400 * 4);

  // ---- 0. zero hx EVERY call (stale tags would satisfy polls across graph replays) ----
  hipMemsetAsync(hx, 0, (size_t)B * 2 * 400 * 8, stream);

  // ---- 1. weight conversions (fused) ----
  cvt_all<<<(980000 + 255) / 256, 256, 0, stream>>>(ctx_wi, ctx_wibf, mod0_wi, mod0_wibf,
                                                    mod1_wi, mod1_wibf, enc_wi, enc_wibf,
                                                    w1, w1bf);

  // ---- 2. ctx input projections, embedding gather FUSED into A-staging ----
  gemm_mfma<bf16, true, true><<<dim3(BT / 128, 5), 256, 0, stream>>>(
      nullptr, x_word, embed, ctx_wibf, ctx_bi, xwFB, BT, 600, 100);
  gemm_mfma<bf16, true, true><<<dim3(BL / 128, 5), 256, 0, stream>>>(
      nullptr, x_query, embed, ctx_wibf, ctx_bi, xwq, BL, 600, 100);

  // ---- 3. ctx scans: word (T=512) and query (L=64) merged into one launch ----
  gru_scan100_dual<float><<<dim3(B, 4), 192, 0, stream>>>(
      xwFB, xwq, ctx_wh, ctx_bh, h_cat, u_cat, T, L);

  // ---- 4. attention ----
  attn_main<<<dim3(B, T / 32), 256, 0, stream>>>(h_cat, u_cat, w_sim, c2q, smaxb, T);
  softmax_q2c<<<B, 256, 0, stream>>>(smaxb, h_cat, q2cb, T);
  build_G<<<(BT * 200 + 255) / 256, 256, 0, stream>>>(h_cat, c2q, q2cb, G, T);

  // ---- 5. mod0 ----
  gemm_mfma<bf16, true, false><<<dim3(BT / 128, 5), 256, 0, stream>>>(
      G, nullptr, nullptr, mod0_wibf, mod0_bi, xwFB, BT, 600, 800);
  gru_scan100_dual<bf16><<<dim3(B, 2), 192, 0, stream>>>(
      xwFB, nullptr, mod0_wh, mod0_bh, M0bf, nullptr, T, T);

  // ---- 6. mod1 ----
  gemm_mfma<bf16, true, false><<<dim3(BT / 128, 5), 256, 0, stream>>>(
      M0bf, nullptr, nullptr, mod1_wibf, mod1_bi, xwFB, BT, 600, 200);
  gru_scan100_dual<bf16><<<dim3(B, 2), 192, 0, stream>>>(
      xwFB, nullptr, mod1_wh, mod1_bh, Mxbf, nullptr, T, T);

  // ---- 7. encoder ----
  gemm_mfma<bf16, true, false><<<dim3(BT / 128, 10), 256, 0, stream>>>(
      Mxbf, nullptr, nullptr, enc_wibf, enc_bi, xwe, BT, 1200, 200);
  gru_scan_enc_tag<<<dim3(B, 8), 640, 0, stream>>>(xwe, enc_wh, enc_bh, enc_outbf, hx, T);
  gemm_mfma<float, false, false><<<dim3(BT / 128, 2), 256, 0, stream>>>(
      enc_outbf, nullptr, nullptr, w1bf, nullptr, encw1, BT, 200, 400);

  // ---- 8. pointer decoder (fused logits + log_softmax) ----
  decoder_small<<<1, 512, 0, stream>>>(dec_wh, dec_bi, dec_bh, w2, d2);
  logits_lsm<<<B, 512, 0, stream>>>(encw1, d2, vt, out_f, T);
}

// Round 14
// 2896.964 us; speedup vs baseline: 1.1019x; 1.0994x over previous
//
#include <hip/hip_runtime.h>
#include <hip/hip_bf16.h>

typedef __hip_bfloat16 bf16;
typedef unsigned long long u64;
typedef __attribute__((ext_vector_type(8))) short s8v;
typedef __attribute__((ext_vector_type(4))) short s4v;
typedef __attribute__((ext_vector_type(4))) float f4v;

#define DEV __device__ __forceinline__

DEV float to_f32(float x) { return x; }
DEV float to_f32(bf16 x) { return __bfloat162float(x); }
DEV void store_c(float* p, float v) { *p = v; }
DEV void store_c(bf16* p, float v) { *p = __float2bfloat16(v); }
DEV float sigmf(float x) { return 1.f / (1.f + __expf(-x)); }
DEV short f2bs(float x) { bf16 h = __float2bfloat16(x); return *(short*)&h; }

// ---------------- fused f32->bf16 conversion of all 5 weight blocks ----------------
__global__ void cvt_all(const float* __restrict__ s0, bf16* __restrict__ d0,   // 60000
                        const float* __restrict__ s1, bf16* __restrict__ d1,   // 480000
                        const float* __restrict__ s2, bf16* __restrict__ d2,   // 120000
                        const float* __restrict__ s3, bf16* __restrict__ d3,   // 240000
                        const float* __restrict__ s4, bf16* __restrict__ d4) { // 80000
  int i = blockIdx.x * blockDim.x + threadIdx.x;
  if (i < 60000) d0[i] = __float2bfloat16(s0[i]);
  i -= 60000;
  if (i >= 0 && i < 480000) d1[i] = __float2bfloat16(s1[i]);
  i -= 480000;
  if (i >= 0 && i < 120000) d2[i] = __float2bfloat16(s2[i]);
  i -= 120000;
  if (i >= 0 && i < 240000) d3[i] = __float2bfloat16(s3[i]);
  i -= 240000;
  if (i >= 0 && i < 80000) d4[i] = __float2bfloat16(s4[i]);
}

// ---------------- MFMA GEMM 128x128, double-buffered LDS pipeline -------------------------
template <typename TC, bool HAS_BIAS, bool GATHER>
__global__ __launch_bounds__(256) void gemm_mfma(
    const bf16* __restrict__ A, const int* __restrict__ idx,
    const float* __restrict__ embedp, const bf16* __restrict__ W,
    const float* __restrict__ bias, TC* __restrict__ C,
    int M, int N, int K) {
  __shared__ short Als[2][128 * 32];
  __shared__ short Wls[2][128 * 32];
  const int tid = threadIdx.x;
  const int m0 = blockIdx.x * 128;
  const int n0 = blockIdx.y * 128;
  const int lane = tid & 63;
  const int wv = tid >> 6;
  const int wm = wv >> 1, wn = wv & 1;
  const int lq = lane >> 4, lr = lane & 15;
  const int row2 = tid >> 1;
  const int half = tid & 1;

  int vrow = 0;
  if (GATHER) vrow = idx[m0 + row2];
  const int nrow = n0 + row2;

  s4v ra[4], rw[4];
  auto load_regs = [&](int k0) {
#pragma unroll
    for (int ss = 0; ss < 4; ++ss) {
      int kk = k0 + half * 16 + ss * 4;
      if (GATHER) {
        if (kk + 4 <= K) {
          float4 a4 = *(const float4*)(embedp + (size_t)vrow * 100 + kk);
          ra[ss] = (s4v){f2bs(a4.x), f2bs(a4.y), f2bs(a4.z), f2bs(a4.w)};
        } else {
          s4v v = {0, 0, 0, 0};
#pragma unroll
          for (int j = 0; j < 4; ++j)
            if (kk + j < K) v[j] = f2bs(embedp[(size_t)vrow * 100 + kk + j]);
          ra[ss] = v;
        }
      } else {
        const short* src = (const short*)(A + (size_t)(m0 + row2) * K + kk);
        if (kk + 4 <= K) {
          ra[ss] = *(const s4v*)src;
        } else {
          s4v v = {0, 0, 0, 0};
#pragma unroll
          for (int j = 0; j < 4; ++j)
            if (kk + j < K) v[j] = src[j];
          ra[ss] = v;
        }
      }
      if (nrow < N) {
        const short* src = (const short*)(W + (size_t)nrow * K + kk);
        if (kk + 4 <= K) {
          rw[ss] = *(const s4v*)src;
        } else {
          s4v v = {0, 0, 0, 0};
#pragma unroll
          for (int j = 0; j < 4; ++j)
            if (kk + j < K) v[j] = src[j];
          rw[ss] = v;
        }
      } else {
        rw[ss] = (s4v){0, 0, 0, 0};
      }
    }
  };
  auto write_lds = [&](int buf) {
#pragma unroll
    for (int ss = 0; ss < 4; ++ss) {
      *(s4v*)&Als[buf][row2 * 32 + half * 16 + ss * 4] = ra[ss];
      *(s4v*)&Wls[buf][row2 * 32 + half * 16 + ss * 4] = rw[ss];
    }
  };

  f4v acc[4][4];
#pragma unroll
  for (int i = 0; i < 4; ++i)
#pragma unroll
    for (int j = 0; j < 4; ++j) acc[i][j] = (f4v){0.f, 0.f, 0.f, 0.f};

  const int nk = (K + 31) / 32;
  load_regs(0);
  write_lds(0);
  __syncthreads();
  int cur = 0;
  for (int ki = 0; ki < nk; ++ki) {
    if (ki + 1 < nk) load_regs((ki + 1) * 32);
    s8v af[4], bfr[4];
#pragma unroll
    for (int mi = 0; mi < 4; ++mi) {
      int r = wm * 64 + mi * 16 + lr;
      af[mi] = *(const s8v*)&Als[cur][r * 32 + lq * 8];
    }
#pragma unroll
    for (int ni = 0; ni < 4; ++ni) {
      int r = wn * 64 + ni * 16 + lr;
      bfr[ni] = *(const s8v*)&Wls[cur][r * 32 + lq * 8];
    }
#pragma unroll
    for (int mi = 0; mi < 4; ++mi)
#pragma unroll
      for (int ni = 0; ni < 4; ++ni)
        acc[mi][ni] = __builtin_amdgcn_mfma_f32_16x16x32_bf16(af[mi], bfr[ni], acc[mi][ni], 0, 0, 0);
    if (ki + 1 < nk) write_lds(cur ^ 1);
    __syncthreads();
    cur ^= 1;
  }
#pragma unroll
  for (int mi = 0; mi < 4; ++mi) {
#pragma unroll
    for (int ni = 0; ni < 4; ++ni) {
      int n = n0 + wn * 64 + ni * 16 + lr;
      if (n >= N) continue;
      float bv = HAS_BIAS ? bias[n] : 0.f;
#pragma unroll
      for (int r = 0; r < 4; ++r) {
        int m = m0 + wm * 64 + mi * 16 + lq * 4 + r;
        store_c(&C[(size_t)m * N + n], acc[mi][ni][r] + bv);
      }
    }
  }
}

// ---------------- GRU scan H=100: ONE barrier/step, per-element gate ownership ------------
// Thread (i=tid>>1, half=tid&1): holds r/z/n gate rows for element i over k-half
// [half*50, half*50+50) (150 weight VGPRs). Pair-combine via shfl_xor(1) (same wave).
// h_s double-buffered by step parity -> the gate-read / update-write hazard disappears,
// leaving ONE __syncthreads per step (orders h[cur^1] writes before next step's reads).
template <typename TO>
__global__ __launch_bounds__(256) void gru_scan100_1b(
    const bf16* __restrict__ xw0, const bf16* __restrict__ xw1,
    const float* __restrict__ wh,  // [2][300][100]
    const float* __restrict__ bh,  // [2][300]
    TO* __restrict__ out0, TO* __restrict__ out1,
    int T0, int T1) {
  const int b = blockIdx.x;
  const int y = blockIdx.y;
  const int which = y >> 1, dir = y & 1;
  const bf16* xw = which ? xw1 : xw0;
  TO* out = which ? out1 : out0;
  const int T = which ? T1 : T0;
  __shared__ float h_s[2][100];
  const int tid = threadIdx.x;
  const int i = tid >> 1, half = tid & 1;
  const bool act = (tid < 200);
  float wr[50], wz[50], wn[50];
  float br = 0.f, bz = 0.f, bn = 0.f;
  if (act) {
    const float* wb = wh + (size_t)dir * 30000;
    const float* rowr = wb + (size_t)i * 100 + half * 50;
    const float* rowz = wb + (size_t)(100 + i) * 100 + half * 50;
    const float* rown = wb + (size_t)(200 + i) * 100 + half * 50;
#pragma unroll
    for (int c = 0; c < 25; ++c) {
      float2 vr = *(const float2*)(rowr + 2 * c);
      wr[2 * c] = vr.x; wr[2 * c + 1] = vr.y;
      float2 vz = *(const float2*)(rowz + 2 * c);
      wz[2 * c] = vz.x; wz[2 * c + 1] = vz.y;
      float2 vn = *(const float2*)(rown + 2 * c);
      wn[2 * c] = vn.x; wn[2 * c + 1] = vn.y;
    }
    if (half == 0) {
      br = bh[dir * 300 + i];
      bz = bh[dir * 300 + 100 + i];
      bn = bh[dir * 300 + 200 + i];
    }
  }
  if (tid < 100) h_s[0][tid] = 0.f;
  float pxr = 0.f, pxz = 0.f, pxn = 0.f;
  if (act && half == 0) {
    int t0 = dir ? (T - 1) : 0;
    size_t base = ((size_t)b * T + t0) * 600 + dir * 300;
    pxr = to_f32(xw[base + i]);
    pxz = to_f32(xw[base + 100 + i]);
    pxn = to_f32(xw[base + 200 + i]);
  }
  __syncthreads();
  int cur = 0;
  for (int step = 0; step < T; ++step) {
    int t = dir ? (T - 1 - step) : step;
    if (act) {
      const float* hp = &h_s[cur][half * 50];
      float a0 = br, a1 = 0.f, z0 = bz, z1 = 0.f, n0 = bn, n1 = 0.f;
#pragma unroll
      for (int c = 0; c < 25; ++c) {
        float2 h2 = *(const float2*)(hp + 2 * c);
        a0 += wr[2 * c] * h2.x; a1 += wr[2 * c + 1] * h2.y;
        z0 += wz[2 * c] * h2.x; z1 += wz[2 * c + 1] * h2.y;
        n0 += wn[2 * c] * h2.x; n1 += wn[2 * c + 1] * h2.y;
      }
      float gr = a0 + a1, gz = z0 + z1, gn = n0 + n1;
      gr += __shfl_xor(gr, 1);
      gz += __shfl_xor(gz, 1);
      gn += __shfl_xor(gn, 1);
      if (half == 0) {
        float hprev = h_s[cur][i];
        float rr = sigmf(pxr + gr);
        float zz = sigmf(pxz + gz);
        float nn = tanhf(pxn + rr * gn);
        float hn = (1.f - zz) * nn + zz * hprev;
        h_s[cur ^ 1][i] = hn;
        store_c(&out[((size_t)b * T + t) * 200 + dir * 100 + i], hn);
        if (step + 1 < T) {
          int tn = dir ? (T - 2 - step) : (step + 1);
          size_t basen = ((size_t)b * T + tn) * 600 + dir * 300;
          pxr = to_f32(xw[basen + i]);
          pxz = to_f32(xw[basen + 100 + i]);
          pxn = to_f32(xw[basen + 200 + i]);
        }
      }
    }
    __syncthreads();
    cur ^= 1;
  }
}

// ---------------- encoder GRU scan H=400: tagged exchange (structural floor shape) ---------
__global__ __launch_bounds__(640) void gru_scan_enc_tag(
    const bf16* __restrict__ xw,   // [B,T,1200]
    const float* __restrict__ wh,  // [1200,400] raw
    const float* __restrict__ bh,  // [1200]
    bf16* __restrict__ out,        // [B,T,400]
    u64* __restrict__ hx,          // [B,2,400] {value,tag} (pre-zeroed EVERY call)
    int T) {
  const int b = blockIdx.x, s = blockIdx.y;
  __shared__ float h_s[400];
  __shared__ float g_s[150];
  const int tid = threadIdx.x;
  const int g = tid >> 2, p = tid & 3;
  const bool active = (tid < 600);
  float w[100];
  float bias = 0.f;
  if (active) {
    int i = g % 50, grp = g / 50;
    int gidx = grp * 400 + s * 50 + i;
    const float* wrow = wh + (size_t)gidx * 400 + p * 100;
#pragma unroll
    for (int c = 0; c < 25; ++c) {
      float4 v = *(const float4*)(wrow + 4 * c);
      w[4 * c] = v.x; w[4 * c + 1] = v.y; w[4 * c + 2] = v.z; w[4 * c + 3] = v.w;
    }
    if (p == 0) bias = bh[gidx];
  }
  for (int k = tid; k < 400; k += 640) h_s[k] = 0.f;
  const int myi = s * 50 + tid;
  float pxr = 0.f, pxz = 0.f, pxn = 0.f;
  if (tid < 50) {
    size_t base0 = (size_t)b * T * 1200;
    pxr = to_f32(xw[base0 + myi]);
    pxz = to_f32(xw[base0 + 400 + myi]);
    pxn = to_f32(xw[base0 + 800 + myi]);
  }
  __syncthreads();

  for (int t = 0; t < T; ++t) {
    if (active) {
      const int hb = p * 100;
      float4 hbuf[25];
#pragma unroll
      for (int c = 0; c < 25; ++c) hbuf[c] = *(const float4*)(&h_s[hb + 4 * c]);
      float a0 = bias, a1 = 0.f, a2 = 0.f, a3 = 0.f;
#pragma unroll
      for (int c = 0; c < 25; ++c) {
        a0 += w[4 * c] * hbuf[c].x; a1 += w[4 * c + 1] * hbuf[c].y;
        a2 += w[4 * c + 2] * hbuf[c].z; a3 += w[4 * c + 3] * hbuf[c].w;
      }
      float acc = (a0 + a1) + (a2 + a3);
      acc += __shfl_xor(acc, 1);
      acc += __shfl_xor(acc, 2);
      if (p == 0) g_s[g] = acc;
    }
    __syncthreads();
    const int par = (t + 1) & 1;
    u64* hxp = hx + ((size_t)b * 2 + par) * 400;
    if (tid < 50) {
      float rr = sigmf(pxr + g_s[tid]);
      float zz = sigmf(pxz + g_s[50 + tid]);
      float nn = tanhf(pxn + rr * g_s[100 + tid]);
      float hn = (1.f - zz) * nn + zz * h_s[myi];
      out[((size_t)b * T + t) * 400 + myi] = __float2bfloat16(hn);
      h_s[myi] = hn;
      u64 pack = (u64)__float_as_uint(hn) | ((u64)(unsigned)(t + 1) << 32);
      __hip_atomic_store(&hxp[myi], pack, __ATOMIC_RELAXED, __HIP_MEMORY_SCOPE_AGENT);
      if (t + 1 < T) {
        size_t basen = ((size_t)b * T + (t + 1)) * 1200;
        pxr = to_f32(xw[basen + myi]);
        pxz = to_f32(xw[basen + 400 + myi]);
        pxn = to_f32(xw[basen + 800 + myi]);
      }
    }
    if (tid < 400 && (tid / 50) != s) {
      const u64* src = &hxp[tid];
      u64 v;
      for (;;) {
        v = __hip_atomic_load(src, __ATOMIC_RELAXED, __HIP_MEMORY_SCOPE_AGENT);
        if ((unsigned)(v >> 32) == (unsigned)(t + 1)) break;
        __builtin_amdgcn_s_sleep(1);
      }
      h_s[tid] = __uint_as_float((unsigned)v);
    }
    __syncthreads();
  }
}

// ---------------- attention with fused trilinear terms ----------------
__global__ __launch_bounds__(256) void attn_main(
    const float* __restrict__ h, const float* __restrict__ u,
    const float* __restrict__ w_sim, float* __restrict__ c2q,
    float* __restrict__ smax, int T) {
  const int b = blockIdx.x;
  const int t0 = blockIdx.y * 32;
  __shared__ float u_s[64 * 201];
  __shared__ float w1_s[200], w2_s[200], w3_s[200];
  __shared__ float th_s[32], tu_s[64];
  __shared__ float hw3_s[200];
  __shared__ float Sp[4][64];
  __shared__ float A_s[64];
  const int tid = threadIdx.x;
  for (int i = tid; i < 64 * 200; i += 256) {
    int l = i / 200, d = i - l * 200;
    u_s[l * 201 + d] = u[((size_t)b * 64 + l) * 200 + d];
  }
  if (tid < 200) {
    w1_s[tid] = w_sim[tid];
    w2_s[tid] = w_sim[200 + tid];
    w3_s[tid] = w_sim[400 + tid];
  }
  __syncthreads();
  {
    int r = tid >> 2, sg = tid & 3;
    float p = 0.f;
    for (int j = 0; j < 50; ++j) p += u_s[r * 201 + sg * 50 + j] * w2_s[sg * 50 + j];
    p += __shfl_down(p, 2);
    p += __shfl_down(p, 1);
    if (sg == 0) tu_s[r] = p;
  }
  {
    int r = tid >> 3, sg = tid & 7;
    float p = 0.f;
    const float* hr = h + ((size_t)b * T + t0 + r) * 200 + sg * 25;
    for (int j = 0; j < 25; ++j) p += hr[j] * w1_s[sg * 25 + j];
    p += __shfl_down(p, 4);
    p += __shfl_down(p, 2);
    p += __shfl_down(p, 1);
    if (sg == 0) th_s[r] = p;
  }
  __syncthreads();
  for (int tt = 0; tt < 32; ++tt) {
    int t = t0 + tt;
    if (tid < 200) hw3_s[tid] = h[((size_t)b * T + t) * 200 + tid] * w3_s[tid];
    __syncthreads();
    int l = tid & 63, q = tid >> 6;
    float p = 0.f;
    for (int d = q * 50; d < q * 50 + 50; ++d) p += hw3_s[d] * u_s[l * 201 + d];
    Sp[q][l] = p;
    __syncthreads();
    if (tid < 64) {
      float s = th_s[tt] + tu_s[l] + Sp[0][l] + Sp[1][l] + Sp[2][l] + Sp[3][l];
      float m = s;
      for (int off = 32; off; off >>= 1) m = fmaxf(m, __shfl_xor(m, off));
      float e = __expf(s - m);
      float ssum = e;
      for (int off = 32; off; off >>= 1) ssum += __shfl_xor(ssum, off);
      A_s[l] = e / ssum;
      if (l == 0) smax[b * T + t] = m;
    }
    __syncthreads();
    if (tid < 200) {
      float acc = 0.f;
      for (int l2 = 0; l2 < 64; ++l2) acc += A_s[l2] * u_s[l2 * 201 + tid];
      c2q[((size_t)b * T + t) * 200 + tid] = acc;
    }
    __syncthreads();
  }
}

// ---------------- fused: batt = softmax(smax row); q2c = sum_t batt*h ----------------
__global__ __launch_bounds__(256) void softmax_q2c(
    const float* __restrict__ smaxv, const float* __restrict__ h,
    float* __restrict__ q2c, int T) {
  int b = blockIdx.x;
  int tid = threadIdx.x;
  __shared__ float red[256];
  __shared__ float batt_s[512];
  float m = -1e30f;
  for (int t = tid; t < T; t += 256) m = fmaxf(m, smaxv[b * T + t]);
  red[tid] = m;
  __syncthreads();
  for (int s = 128; s; s >>= 1) {
    if (tid < s) red[tid] = fmaxf(red[tid], red[tid + s]);
    __syncthreads();
  }
  m = red[0];
  __syncthreads();
  float sum = 0.f;
  for (int t = tid; t < T; t += 256) {
    float e = __expf(smaxv[b * T + t] - m);
    batt_s[t] = e;
    sum += e;
  }
  red[tid] = sum;
  __syncthreads();
  for (int s = 128; s; s >>= 1) {
    if (tid < s) red[tid] += red[tid + s];
    __syncthreads();
  }
  float inv = 1.f / red[0];
  __syncthreads();
  if (tid < 200) {
    float acc = 0.f;
    for (int t = 0; t < T; ++t) acc += batt_s[t] * h[((size_t)b * T + t) * 200 + tid];
    q2c[b * 200 + tid] = acc * inv;
  }
}

// ---------------- G = [h, c2q, h*c2q, h*q2c] (bf16) ----------------
__global__ void build_G(const float* __restrict__ h, const float* __restrict__ c2q,
                        const float* __restrict__ q2c, bf16* __restrict__ G, int T) {
  size_t i = (size_t)blockIdx.x * blockDim.x + threadIdx.x;
  if (i >= (size_t)32 * T * 200) return;
  size_t row = i / 200;
  int d = (int)(i - row * 200);
  int b = (int)(row / T);
  float hv = h[i];
  float cv = c2q[i];
  float qv = q2c[b * 200 + d];
  bf16* g = G + row * 800;
  g[d] = __float2bfloat16(hv);
  g[200 + d] = __float2bfloat16(cv);
  g[400 + d] = __float2bfloat16(hv * cv);
  g[600 + d] = __float2bfloat16(hv * qv);
}

// ---------------- decoder (batch-uniform since dec_in == 0): d2[2][200] ----------------
__global__ __launch_bounds__(512) void decoder_small(
    const float* __restrict__ dwh, const float* __restrict__ dbi,
    const float* __restrict__ dbh, const float* __restrict__ w2,
    float* __restrict__ d2out) {
  __shared__ float hid[400];
  __shared__ float hid2[400];
  __shared__ float gh[1200];
  const int tid = threadIdx.x;
  if (tid < 400) {
    float r = sigmf(dbi[tid] + dbh[tid]);
    float z = sigmf(dbi[400 + tid] + dbh[400 + tid]);
    float n = tanhf(dbi[800 + tid] + r * dbh[800 + tid]);
    hid[tid] = (1.f - z) * n;
  }
  __syncthreads();
  if (tid < 200) {
    float a = 0.f;
    for (int k = 0; k < 400; ++k) a += w2[(size_t)tid * 400 + k] * hid[k];
    d2out[tid] = a;
  }
  for (int j = tid; j < 1200; j += 512) {
    float a = dbh[j];
    for (int k = 0; k < 400; ++k) a += dwh[(size_t)j * 400 + k] * hid[k];
    gh[j] = a;
  }
  __syncthreads();
  if (tid < 400) {
    float r = sigmf(dbi[tid] + gh[tid]);
    float z = sigmf(dbi[400 + tid] + gh[400 + tid]);
    float n = tanhf(dbi[800 + tid] + r * gh[800 + tid]);
    hid2[tid] = (1.f - z) * n + z * hid[tid];
  }
  __syncthreads();
  if (tid < 200) {
    float a = 0.f;
    for (int k = 0; k < 400; ++k) a += w2[(size_t)tid * 400 + k] * hid2[k];
    d2out[200 + tid] = a;
  }
}

// ---------------- fused logits + log_softmax: one block per batch ----------------
__global__ __launch_bounds__(512) void logits_lsm(
    const float* __restrict__ encw1, const float* __restrict__ d2,
    const float* __restrict__ vt, float* __restrict__ outp, int T) {
  int b = blockIdx.x;
  __shared__ float lg[2][512];
  __shared__ float red[512];
  const int tid = threadIdx.x;
  const int wave = tid >> 6, lane = tid & 63;
  for (int r = wave; r < T; r += 8) {
    const float* e = encw1 + ((size_t)b * T + r) * 200;
    float s0 = 0.f, s1 = 0.f;
    for (int p = lane; p < 200; p += 64) {
      float ev = e[p], v = vt[p];
      s0 += tanhf(ev + d2[p]) * v;
      s1 += tanhf(ev + d2[200 + p]) * v;
    }
    for (int off = 32; off; off >>= 1) {
      s0 += __shfl_down(s0, off);
      s1 += __shfl_down(s1, off);
    }
    if (lane == 0) { lg[0][r] = s0; lg[1][r] = s1; }
  }
  __syncthreads();
  for (int it = 0; it < 2; ++it) {
    red[tid] = lg[it][tid];
    __syncthreads();
    for (int s = 256; s; s >>= 1) {
      if (tid < s) red[tid] = fmaxf(red[tid], red[tid + s]);
      __syncthreads();
    }
    float m = red[0];
    __syncthreads();
    red[tid] = __expf(lg[it][tid] - m);
    __syncthreads();
    for (int s = 256; s; s >>= 1) {
      if (tid < s) red[tid] += red[tid + s];
      __syncthreads();
    }
    float lse = m + __logf(red[0]);
    __syncthreads();
    outp[((size_t)b * 2 + it) * T + tid] = lg[it][tid] - lse;
  }
}

extern "C" void kernel_launch(void* const* d_in, const int* in_sizes, int n_in,
                              void* d_out, int out_size, void* d_ws, size_t ws_size,
                              hipStream_t stream) {
  (void)in_sizes; (void)n_in; (void)out_size; (void)ws_size;
  const int B = 32, T = 512, L = 64;
  const int BT = B * T;
  const int BL = B * L;

  const int* x_word = (const int*)d_in[0];
  const int* x_query = (const int*)d_in[1];
  const float* embed = (const float*)d_in[2];
  const float* ctx_wi = (const float*)d_in[3];
  const float* ctx_wh = (const float*)d_in[4];
  const float* ctx_bi = (const float*)d_in[5];
  const float* ctx_bh = (const float*)d_in[6];
  const float* mod0_wi = (const float*)d_in[7];
  const float* mod0_wh = (const float*)d_in[8];
  const float* mod0_bi = (const float*)d_in[9];
  const float* mod0_bh = (const float*)d_in[10];
  const float* mod1_wi = (const float*)d_in[11];
  const float* mod1_wh = (const float*)d_in[12];
  const float* mod1_bi = (const float*)d_in[13];
  const float* mod1_bh = (const float*)d_in[14];
  const float* w_sim = (const float*)d_in[15];
  const float* enc_wi = (const float*)d_in[16];
  const float* enc_wh = (const float*)d_in[17];
  const float* enc_bi = (const float*)d_in[18];
  const float* enc_bh = (const float*)d_in[19];
  const float* dec_wh = (const float*)d_in[21];
  const float* dec_bi = (const float*)d_in[22];
  const float* dec_bh = (const float*)d_in[23];
  const float* w1 = (const float*)d_in[24];
  const float* w2 = (const float*)d_in[25];
  const float* vt = (const float*)d_in[26];
  float* out_f = (float*)d_out;

  char* ws = (char*)d_ws;
  size_t off = 0;
  auto alloc = [&](size_t bytes) -> void* {
    void* p = ws + off;
    off += (bytes + 255) & ~(size_t)255;
    return p;
  };
  u64* hx = (u64*)alloc((size_t)B * 2 * 400 * 8);
  bf16* ctx_wibf = (bf16*)alloc((size_t)60000 * 2);
  bf16* mod0_wibf = (bf16*)alloc((size_t)480000 * 2);
  bf16* mod1_wibf = (bf16*)alloc((size_t)120000 * 2);
  bf16* enc_wibf = (bf16*)alloc((size_t)240000 * 2);
  bf16* w1bf = (bf16*)alloc((size_t)80000 * 2);
  char* RA = (char*)alloc((size_t)BT * 1200 * 2);  // xw [BT,600] or xwe [BT,1200]
  bf16* xwFB = (bf16*)RA;
  bf16* xwe = (bf16*)RA;
  bf16* xwq = (bf16*)alloc((size_t)BL * 600 * 2);
  char* RB = (char*)alloc((size_t)BT * 800 * 2);
  bf16* G = (bf16*)RB;
  bf16* enc_outbf = (bf16*)RB;
  char* RC = (char*)alloc((size_t)2 * BT * 200 * 4);
  float* h_cat = (float*)RC;
  float* c2q = (float*)(RC + (size_t)BT * 200 * 4);
  bf16* M0bf = (bf16*)c2q;
  bf16* Mxbf = (bf16*)h_cat;
  float* encw1 = c2q;
  float* u_cat = (float*)alloc((size_t)BL * 200 * 4);
  float* smaxb = (float*)alloc((size_t)BT * 4);
  float* q2cb = (float*)alloc((size_t)B * 200 * 4);
  float* d2 = (float*)alloc((size_t)400 * 4);

  // ---- 0. zero hx EVERY call (stale tags would satisfy polls across graph replays) ----
  hipMemsetAsync(hx, 0, (size_t)B * 2 * 400 * 8, stream);

  // ---- 1. weight conversions (fused) ----
  cvt_all<<<(980000 + 255) / 256, 256, 0, stream>>>(ctx_wi, ctx_wibf, mod0_wi, mod0_wibf,
                                                    mod1_wi, mod1_wibf, enc_wi, enc_wibf,
                                                    w1, w1bf);

  // ---- 2. ctx input projections, embedding gather FUSED into A-staging ----
  gemm_mfma<bf16, true, true><<<dim3(BT / 128, 5), 256, 0, stream>>>(
      nullptr, x_word, embed, ctx_wibf, ctx_bi, xwFB, BT, 600, 100);
  gemm_mfma<bf16, true, true><<<dim3(BL / 128, 5), 256, 0, stream>>>(
      nullptr, x_query, embed, ctx_wibf, ctx_bi, xwq, BL, 600, 100);

  // ---- 3. ctx scans: word (T=512) and query (L=64) merged into one launch ----
  gru_scan100_1b<float><<<dim3(B, 4), 256, 0, stream>>>(
      xwFB, xwq, ctx_wh, ctx_bh, h_cat, u_cat, T, L);

  // ---- 4. attention ----
  attn_main<<<dim3(B, T / 32), 256, 0, stream>>>(h_cat, u_cat, w_sim, c2q, smaxb, T);
  softmax_q2c<<<B, 256, 0, stream>>>(smaxb, h_cat, q2cb, T);
  build_G<<<(BT * 200 + 255) / 256, 256, 0, stream>>>(h_cat, c2q, q2cb, G, T);

  // ---- 5. mod0 ----
  gemm_mfma<bf16, true, false><<<dim3(BT / 128, 5), 256, 0, stream>>>(
      G, nullptr, nullptr, mod0_wibf, mod0_bi, xwFB, BT, 600, 800);
  gru_scan100_1b<bf16><<<dim3(B, 2), 256, 0, stream>>>(
      xwFB, nullptr, mod0_wh, mod0_bh, M0bf, nullptr, T, T);

  // ---- 6. mod1 ----
  gemm_mfma<bf16, true, false><<<dim3(BT / 128, 5), 256, 0, stream>>>(
      M0bf, nullptr, nullptr, mod1_wibf, mod1_bi, xwFB, BT, 600, 200);
  gru_scan100_1b<bf16><<<dim3(B, 2), 256, 0, stream>>>(
      xwFB, nullptr, mod1_wh, mod1_bh, Mxbf, nullptr, T, T);

  // ---- 7. encoder ----
  gemm_mfma<bf16, true, false><<<dim3(BT / 128, 10), 256, 0, stream>>>(
      Mxbf, nullptr, nullptr, enc_wibf, enc_bi, xwe, BT, 1200, 200);
  gru_scan_enc_tag<<<dim3(B, 8), 640, 0, stream>>>(xwe, enc_wh, enc_bh, enc_outbf, hx, T);
  gemm_mfma<float, false, false><<<dim3(BT / 128, 2), 256, 0, stream>>>(
      enc_outbf, nullptr, nullptr, w1bf, nullptr, encw1, BT, 200, 400);

  // ---- 8. pointer decoder (fused logits + log_softmax) ----
  decoder_small<<<1, 512, 0, stream>>>(dec_wh, dec_bi, dec_bh, w2, d2);
  logits_lsm<<<B, 512, 0, stream>>>(encw1, d2, vt, out_f, T);
}

// Round 15
// 2873.967 us; speedup vs baseline: 1.1107x; 1.0080x over previous
//
#include <hip/hip_runtime.h>
#include <hip/hip_bf16.h>

typedef __hip_bfloat16 bf16;
typedef unsigned long long u64;
typedef __attribute__((ext_vector_type(8))) short s8v;
typedef __attribute__((ext_vector_type(4))) short s4v;
typedef __attribute__((ext_vector_type(4))) float f4v;

#define DEV __device__ __forceinline__

DEV float to_f32(float x) { return x; }
DEV float to_f32(bf16 x) { return __bfloat162float(x); }
DEV void store_c(float* p, float v) { *p = v; }
DEV void store_c(bf16* p, float v) { *p = __float2bfloat16(v); }
DEV float sigmf(float x) { return 1.f / (1.f + __expf(-x)); }
DEV short f2bs(float x) { bf16 h = __float2bfloat16(x); return *(short*)&h; }

// ---------------- fused f32->bf16 conversion of all 5 weight blocks ----------------
__global__ void cvt_all(const float* __restrict__ s0, bf16* __restrict__ d0,   // 60000
                        const float* __restrict__ s1, bf16* __restrict__ d1,   // 480000
                        const float* __restrict__ s2, bf16* __restrict__ d2,   // 120000
                        const float* __restrict__ s3, bf16* __restrict__ d3,   // 240000
                        const float* __restrict__ s4, bf16* __restrict__ d4) { // 80000
  int i = blockIdx.x * blockDim.x + threadIdx.x;
  if (i < 60000) d0[i] = __float2bfloat16(s0[i]);
  i -= 60000;
  if (i >= 0 && i < 480000) d1[i] = __float2bfloat16(s1[i]);
  i -= 480000;
  if (i >= 0 && i < 120000) d2[i] = __float2bfloat16(s2[i]);
  i -= 120000;
  if (i >= 0 && i < 240000) d3[i] = __float2bfloat16(s3[i]);
  i -= 240000;
  if (i >= 0 && i < 80000) d4[i] = __float2bfloat16(s4[i]);
}

// ---------------- MFMA GEMM 128x128, double-buffered LDS pipeline -------------------------
template <typename TC, bool HAS_BIAS, bool GATHER>
__global__ __launch_bounds__(256) void gemm_mfma(
    const bf16* __restrict__ A, const int* __restrict__ idx,
    const float* __restrict__ embedp, const bf16* __restrict__ W,
    const float* __restrict__ bias, TC* __restrict__ C,
    int M, int N, int K) {
  __shared__ short Als[2][128 * 32];
  __shared__ short Wls[2][128 * 32];
  const int tid = threadIdx.x;
  const int m0 = blockIdx.x * 128;
  const int n0 = blockIdx.y * 128;
  const int lane = tid & 63;
  const int wv = tid >> 6;
  const int wm = wv >> 1, wn = wv & 1;
  const int lq = lane >> 4, lr = lane & 15;
  const int row2 = tid >> 1;
  const int half = tid & 1;

  int vrow = 0;
  if (GATHER) vrow = idx[m0 + row2];
  const int nrow = n0 + row2;

  s4v ra[4], rw[4];
  auto load_regs = [&](int k0) {
#pragma unroll
    for (int ss = 0; ss < 4; ++ss) {
      int kk = k0 + half * 16 + ss * 4;
      if (GATHER) {
        if (kk + 4 <= K) {
          float4 a4 = *(const float4*)(embedp + (size_t)vrow * 100 + kk);
          ra[ss] = (s4v){f2bs(a4.x), f2bs(a4.y), f2bs(a4.z), f2bs(a4.w)};
        } else {
          s4v v = {0, 0, 0, 0};
#pragma unroll
          for (int j = 0; j < 4; ++j)
            if (kk + j < K) v[j] = f2bs(embedp[(size_t)vrow * 100 + kk + j]);
          ra[ss] = v;
        }
      } else {
        const short* src = (const short*)(A + (size_t)(m0 + row2) * K + kk);
        if (kk + 4 <= K) {
          ra[ss] = *(const s4v*)src;
        } else {
          s4v v = {0, 0, 0, 0};
#pragma unroll
          for (int j = 0; j < 4; ++j)
            if (kk + j < K) v[j] = src[j];
          ra[ss] = v;
        }
      }
      if (nrow < N) {
        const short* src = (const short*)(W + (size_t)nrow * K + kk);
        if (kk + 4 <= K) {
          rw[ss] = *(const s4v*)src;
        } else {
          s4v v = {0, 0, 0, 0};
#pragma unroll
          for (int j = 0; j < 4; ++j)
            if (kk + j < K) v[j] = src[j];
          rw[ss] = v;
        }
      } else {
        rw[ss] = (s4v){0, 0, 0, 0};
      }
    }
  };
  auto write_lds = [&](int buf) {
#pragma unroll
    for (int ss = 0; ss < 4; ++ss) {
      *(s4v*)&Als[buf][row2 * 32 + half * 16 + ss * 4] = ra[ss];
      *(s4v*)&Wls[buf][row2 * 32 + half * 16 + ss * 4] = rw[ss];
    }
  };

  f4v acc[4][4];
#pragma unroll
  for (int i = 0; i < 4; ++i)
#pragma unroll
    for (int j = 0; j < 4; ++j) acc[i][j] = (f4v){0.f, 0.f, 0.f, 0.f};

  const int nk = (K + 31) / 32;
  load_regs(0);
  write_lds(0);
  __syncthreads();
  int cur = 0;
  for (int ki = 0; ki < nk; ++ki) {
    if (ki + 1 < nk) load_regs((ki + 1) * 32);
    s8v af[4], bfr[4];
#pragma unroll
    for (int mi = 0; mi < 4; ++mi) {
      int r = wm * 64 + mi * 16 + lr;
      af[mi] = *(const s8v*)&Als[cur][r * 32 + lq * 8];
    }
#pragma unroll
    for (int ni = 0; ni < 4; ++ni) {
      int r = wn * 64 + ni * 16 + lr;
      bfr[ni] = *(const s8v*)&Wls[cur][r * 32 + lq * 8];
    }
#pragma unroll
    for (int mi = 0; mi < 4; ++mi)
#pragma unroll
      for (int ni = 0; ni < 4; ++ni)
        acc[mi][ni] = __builtin_amdgcn_mfma_f32_16x16x32_bf16(af[mi], bfr[ni], acc[mi][ni], 0, 0, 0);
    if (ki + 1 < nk) write_lds(cur ^ 1);
    __syncthreads();
    cur ^= 1;
  }
#pragma unroll
  for (int mi = 0; mi < 4; ++mi) {
#pragma unroll
    for (int ni = 0; ni < 4; ++ni) {
      int n = n0 + wn * 64 + ni * 16 + lr;
      if (n >= N) continue;
      float bv = HAS_BIAS ? bias[n] : 0.f;
#pragma unroll
      for (int r = 0; r < 4; ++r) {
        int m = m0 + wm * 64 + mi * 16 + lq * 4 + r;
        store_c(&C[(size_t)m * N + n], acc[mi][ni][r] + bv);
      }
    }
  }
}

// ---------------- GRU scan H=100: ONE barrier/step, per-element gate ownership ------------
template <typename TO>
__global__ __launch_bounds__(256) void gru_scan100_1b(
    const bf16* __restrict__ xw0, const bf16* __restrict__ xw1,
    const float* __restrict__ wh,  // [2][300][100]
    const float* __restrict__ bh,  // [2][300]
    TO* __restrict__ out0, TO* __restrict__ out1,
    int T0, int T1) {
  const int b = blockIdx.x;
  const int y = blockIdx.y;
  const int which = y >> 1, dir = y & 1;
  const bf16* xw = which ? xw1 : xw0;
  TO* out = which ? out1 : out0;
  const int T = which ? T1 : T0;
  __shared__ float h_s[2][100];
  const int tid = threadIdx.x;
  const int i = tid >> 1, half = tid & 1;
  const bool act = (tid < 200);
  float wr[50], wz[50], wn[50];
  float br = 0.f, bz = 0.f, bn = 0.f;
  if (act) {
    const float* wb = wh + (size_t)dir * 30000;
    const float* rowr = wb + (size_t)i * 100 + half * 50;
    const float* rowz = wb + (size_t)(100 + i) * 100 + half * 50;
    const float* rown = wb + (size_t)(200 + i) * 100 + half * 50;
#pragma unroll
    for (int c = 0; c < 25; ++c) {
      float2 vr = *(const float2*)(rowr + 2 * c);
      wr[2 * c] = vr.x; wr[2 * c + 1] = vr.y;
      float2 vz = *(const float2*)(rowz + 2 * c);
      wz[2 * c] = vz.x; wz[2 * c + 1] = vz.y;
      float2 vn = *(const float2*)(rown + 2 * c);
      wn[2 * c] = vn.x; wn[2 * c + 1] = vn.y;
    }
    if (half == 0) {
      br = bh[dir * 300 + i];
      bz = bh[dir * 300 + 100 + i];
      bn = bh[dir * 300 + 200 + i];
    }
  }
  if (tid < 100) h_s[0][tid] = 0.f;
  float pxr = 0.f, pxz = 0.f, pxn = 0.f;
  if (act && half == 0) {
    int t0 = dir ? (T - 1) : 0;
    size_t base = ((size_t)b * T + t0) * 600 + dir * 300;
    pxr = to_f32(xw[base + i]);
    pxz = to_f32(xw[base + 100 + i]);
    pxn = to_f32(xw[base + 200 + i]);
  }
  __syncthreads();
  int cur = 0;
  for (int step = 0; step < T; ++step) {
    int t = dir ? (T - 1 - step) : step;
    if (act) {
      const float* hp = &h_s[cur][half * 50];
      float a0 = br, a1 = 0.f, z0 = bz, z1 = 0.f, n0 = bn, n1 = 0.f;
#pragma unroll
      for (int c = 0; c < 25; ++c) {
        float2 h2 = *(const float2*)(hp + 2 * c);
        a0 += wr[2 * c] * h2.x; a1 += wr[2 * c + 1] * h2.y;
        z0 += wz[2 * c] * h2.x; z1 += wz[2 * c + 1] * h2.y;
        n0 += wn[2 * c] * h2.x; n1 += wn[2 * c + 1] * h2.y;
      }
      float gr = a0 + a1, gz = z0 + z1, gn = n0 + n1;
      gr += __shfl_xor(gr, 1);
      gz += __shfl_xor(gz, 1);
      gn += __shfl_xor(gn, 1);
      if (half == 0) {
        float hprev = h_s[cur][i];
        float rr = sigmf(pxr + gr);
        float zz = sigmf(pxz + gz);
        float nn = tanhf(pxn + rr * gn);
        float hn = (1.f - zz) * nn + zz * hprev;
        h_s[cur ^ 1][i] = hn;
        store_c(&out[((size_t)b * T + t) * 200 + dir * 100 + i], hn);
        if (step + 1 < T) {
          int tn = dir ? (T - 2 - step) : (step + 1);
          size_t basen = ((size_t)b * T + tn) * 600 + dir * 300;
          pxr = to_f32(xw[basen + i]);
          pxz = to_f32(xw[basen + 100 + i]);
          pxn = to_f32(xw[basen + 200 + i]);
        }
      }
    }
    __syncthreads();
    cur ^= 1;
  }
}

// ---------------- encoder GRU scan H=400: ONE barrier/step + tagged exchange --------------
// Thread (e=tid>>3, p=tid&7): all three gate rows of element e over k-octant
// [p*50, p*50+50) (150 weight VGPRs). Combine via shfl_xor 1/2/4 (8-lane groups, intra-wave).
// h_s double-buffered by parity: gate phase reads h_s[cur]; owner (p==0) and pollers write
// h_s[cur^1] -> ONE __syncthreads per step. Exchange protocol (tagged relaxed agent atomics,
// parity double-buffer) unchanged from the proven shape.
__global__ __launch_bounds__(448) void gru_scan_enc_1b(
    const bf16* __restrict__ xw,   // [B,T,1200]
    const float* __restrict__ wh,  // [1200,400] raw
    const float* __restrict__ bh,  // [1200]
    bf16* __restrict__ out,        // [B,T,400]
    u64* __restrict__ hx,          // [B,2,400] {value,tag} (pre-zeroed EVERY call)
    int T) {
  const int b = blockIdx.x, s = blockIdx.y;
  __shared__ float h_s[2][400];
  const int tid = threadIdx.x;
  const int e = tid >> 3, p = tid & 7;  // element e in [0,50), k-octant p
  const bool act = (tid < 400);
  const int myi = s * 50 + e;
  float wr[50], wz[50], wn[50];
  float br = 0.f, bz = 0.f, bn = 0.f;
  if (act) {
    int rrow = s * 50 + e, zrow = 400 + s * 50 + e, nrow = 800 + s * 50 + e;
    const float* pr = wh + (size_t)rrow * 400 + p * 50;
    const float* pz = wh + (size_t)zrow * 400 + p * 50;
    const float* pn = wh + (size_t)nrow * 400 + p * 50;
#pragma unroll
    for (int c = 0; c < 25; ++c) {
      float2 vr = *(const float2*)(pr + 2 * c);
      wr[2 * c] = vr.x; wr[2 * c + 1] = vr.y;
      float2 vz = *(const float2*)(pz + 2 * c);
      wz[2 * c] = vz.x; wz[2 * c + 1] = vz.y;
      float2 vn = *(const float2*)(pn + 2 * c);
      wn[2 * c] = vn.x; wn[2 * c + 1] = vn.y;
    }
    if (p == 0) { br = bh[rrow]; bz = bh[zrow]; bn = bh[nrow]; }
  }
  for (int k = tid; k < 400; k += 448) h_s[0][k] = 0.f;
  float pxr = 0.f, pxz = 0.f, pxn = 0.f;
  if (act && p == 0) {
    size_t base0 = (size_t)b * T * 1200;
    pxr = to_f32(xw[base0 + myi]);
    pxz = to_f32(xw[base0 + 400 + myi]);
    pxn = to_f32(xw[base0 + 800 + myi]);
  }
  __syncthreads();
  int cur = 0;
  for (int t = 0; t < T; ++t) {
    float gr = br, gz = bz, gn = bn;
    if (act) {
      const float* hp = &h_s[cur][p * 50];
      float a0 = gr, a1 = 0.f, z0 = gz, z1 = 0.f, n0 = gn, n1 = 0.f;
#pragma unroll
      for (int c = 0; c < 25; ++c) {
        float2 h2 = *(const float2*)(hp + 2 * c);
        a0 += wr[2 * c] * h2.x; a1 += wr[2 * c + 1] * h2.y;
        z0 += wz[2 * c] * h2.x; z1 += wz[2 * c + 1] * h2.y;
        n0 += wn[2 * c] * h2.x; n1 += wn[2 * c + 1] * h2.y;
      }
      gr = a0 + a1; gz = z0 + z1; gn = n0 + n1;
      gr += __shfl_xor(gr, 1); gr += __shfl_xor(gr, 2); gr += __shfl_xor(gr, 4);
      gz += __shfl_xor(gz, 1); gz += __shfl_xor(gz, 2); gz += __shfl_xor(gz, 4);
      gn += __shfl_xor(gn, 1); gn += __shfl_xor(gn, 2); gn += __shfl_xor(gn, 4);
    }
    const int par = (t + 1) & 1;
    u64* hxp = hx + ((size_t)b * 2 + par) * 400;
    if (act && p == 0) {
      float hprev = h_s[cur][myi];
      float rr = sigmf(pxr + gr);
      float zz = sigmf(pxz + gz);
      float nn = tanhf(pxn + rr * gn);
      float hn = (1.f - zz) * nn + zz * hprev;
      out[((size_t)b * T + t) * 400 + myi] = __float2bfloat16(hn);
      h_s[cur ^ 1][myi] = hn;
      u64 pack = (u64)__float_as_uint(hn) | ((u64)(unsigned)(t + 1) << 32);
      __hip_atomic_store(&hxp[myi], pack, __ATOMIC_RELAXED, __HIP_MEMORY_SCOPE_AGENT);
      if (t + 1 < T) {
        size_t basen = ((size_t)b * T + (t + 1)) * 1200;
        pxr = to_f32(xw[basen + myi]);
        pxz = to_f32(xw[basen + 400 + myi]);
        pxn = to_f32(xw[basen + 800 + myi]);
      }
    }
    if (tid < 400 && (tid / 50) != s) {  // pull foreign elements into the next buffer
      const u64* src = &hxp[tid];
      u64 v;
      for (;;) {
        v = __hip_atomic_load(src, __ATOMIC_RELAXED, __HIP_MEMORY_SCOPE_AGENT);
        if ((unsigned)(v >> 32) == (unsigned)(t + 1)) break;
        __builtin_amdgcn_s_sleep(1);
      }
      h_s[cur ^ 1][tid] = __uint_as_float((unsigned)v);
    }
    __syncthreads();
    cur ^= 1;
  }
}

// ---------------- attention with fused trilinear terms ----------------
__global__ __launch_bounds__(256) void attn_main(
    const float* __restrict__ h, const float* __restrict__ u,
    const float* __restrict__ w_sim, float* __restrict__ c2q,
    float* __restrict__ smax, int T) {
  const int b = blockIdx.x;
  const int t0 = blockIdx.y * 32;
  __shared__ float u_s[64 * 201];
  __shared__ float w1_s[200], w2_s[200], w3_s[200];
  __shared__ float th_s[32], tu_s[64];
  __shared__ float hw3_s[200];
  __shared__ float Sp[4][64];
  __shared__ float A_s[64];
  const int tid = threadIdx.x;
  for (int i = tid; i < 64 * 200; i += 256) {
    int l = i / 200, d = i - l * 200;
    u_s[l * 201 + d] = u[((size_t)b * 64 + l) * 200 + d];
  }
  if (tid < 200) {
    w1_s[tid] = w_sim[tid];
    w2_s[tid] = w_sim[200 + tid];
    w3_s[tid] = w_sim[400 + tid];
  }
  __syncthreads();
  {
    int r = tid >> 2, sg = tid & 3;
    float p = 0.f;
    for (int j = 0; j < 50; ++j) p += u_s[r * 201 + sg * 50 + j] * w2_s[sg * 50 + j];
    p += __shfl_down(p, 2);
    p += __shfl_down(p, 1);
    if (sg == 0) tu_s[r] = p;
  }
  {
    int r = tid >> 3, sg = tid & 7;
    float p = 0.f;
    const float* hr = h + ((size_t)b * T + t0 + r) * 200 + sg * 25;
    for (int j = 0; j < 25; ++j) p += hr[j] * w1_s[sg * 25 + j];
    p += __shfl_down(p, 4);
    p += __shfl_down(p, 2);
    p += __shfl_down(p, 1);
    if (sg == 0) th_s[r] = p;
  }
  __syncthreads();
  for (int tt = 0; tt < 32; ++tt) {
    int t = t0 + tt;
    if (tid < 200) hw3_s[tid] = h[((size_t)b * T + t) * 200 + tid] * w3_s[tid];
    __syncthreads();
    int l = tid & 63, q = tid >> 6;
    float p = 0.f;
    for (int d = q * 50; d < q * 50 + 50; ++d) p += hw3_s[d] * u_s[l * 201 + d];
    Sp[q][l] = p;
    __syncthreads();
    if (tid < 64) {
      float s = th_s[tt] + tu_s[l] + Sp[0][l] + Sp[1][l] + Sp[2][l] + Sp[3][l];
      float m = s;
      for (int off = 32; off; off >>= 1) m = fmaxf(m, __shfl_xor(m, off));
      float e = __expf(s - m);
      float ssum = e;
      for (int off = 32; off; off >>= 1) ssum += __shfl_xor(ssum, off);
      A_s[l] = e / ssum;
      if (l == 0) smax[b * T + t] = m;
    }
    __syncthreads();
    if (tid < 200) {
      float acc = 0.f;
      for (int l2 = 0; l2 < 64; ++l2) acc += A_s[l2] * u_s[l2 * 201 + tid];
      c2q[((size_t)b * T + t) * 200 + tid] = acc;
    }
    __syncthreads();
  }
}

// ---------------- fused: batt = softmax(smax row); q2c = sum_t batt*h ----------------
__global__ __launch_bounds__(256) void softmax_q2c(
    const float* __restrict__ smaxv, const float* __restrict__ h,
    float* __restrict__ q2c, int T) {
  int b = blockIdx.x;
  int tid = threadIdx.x;
  __shared__ float red[256];
  __shared__ float batt_s[512];
  float m = -1e30f;
  for (int t = tid; t < T; t += 256) m = fmaxf(m, smaxv[b * T + t]);
  red[tid] = m;
  __syncthreads();
  for (int s = 128; s; s >>= 1) {
    if (tid < s) red[tid] = fmaxf(red[tid], red[tid + s]);
    __syncthreads();
  }
  m = red[0];
  __syncthreads();
  float sum = 0.f;
  for (int t = tid; t < T; t += 256) {
    float e = __expf(smaxv[b * T + t] - m);
    batt_s[t] = e;
    sum += e;
  }
  red[tid] = sum;
  __syncthreads();
  for (int s = 128; s; s >>= 1) {
    if (tid < s) red[tid] += red[tid + s];
    __syncthreads();
  }
  float inv = 1.f / red[0];
  __syncthreads();
  if (tid < 200) {
    float acc = 0.f;
    for (int t = 0; t < T; ++t) acc += batt_s[t] * h[((size_t)b * T + t) * 200 + tid];
    q2c[b * 200 + tid] = acc * inv;
  }
}

// ---------------- G = [h, c2q, h*c2q, h*q2c] (bf16) ----------------
__global__ void build_G(const float* __restrict__ h, const float* __restrict__ c2q,
                        const float* __restrict__ q2c, bf16* __restrict__ G, int T) {
  size_t i = (size_t)blockIdx.x * blockDim.x + threadIdx.x;
  if (i >= (size_t)32 * T * 200) return;
  size_t row = i / 200;
  int d = (int)(i - row * 200);
  int b = (int)(row / T);
  float hv = h[i];
  float cv = c2q[i];
  float qv = q2c[b * 200 + d];
  bf16* g = G + row * 800;
  g[d] = __float2bfloat16(hv);
  g[200 + d] = __float2bfloat16(cv);
  g[400 + d] = __float2bfloat16(hv * cv);
  g[600 + d] = __float2bfloat16(hv * qv);
}

// ---------------- decoder (batch-uniform since dec_in == 0): d2[2][200] ----------------
__global__ __launch_bounds__(512) void decoder_small(
    const float* __restrict__ dwh, const float* __restrict__ dbi,
    const float* __restrict__ dbh, const float* __restrict__ w2,
    float* __restrict__ d2out) {
  __shared__ float hid[400];
  __shared__ float hid2[400];
  __shared__ float gh[1200];
  const int tid = threadIdx.x;
  if (tid < 400) {
    float r = sigmf(dbi[tid] + dbh[tid]);
    float z = sigmf(dbi[400 + tid] + dbh[400 + tid]);
    float n = tanhf(dbi[800 + tid] + r * dbh[800 + tid]);
    hid[tid] = (1.f - z) * n;
  }
  __syncthreads();
  if (tid < 200) {
    float a = 0.f;
    for (int k = 0; k < 400; ++k) a += w2[(size_t)tid * 400 + k] * hid[k];
    d2out[tid] = a;
  }
  for (int j = tid; j < 1200; j += 512) {
    float a = dbh[j];
    for (int k = 0; k < 400; ++k) a += dwh[(size_t)j * 400 + k] * hid[k];
    gh[j] = a;
  }
  __syncthreads();
  if (tid < 400) {
    float r = sigmf(dbi[tid] + gh[tid]);
    float z = sigmf(dbi[400 + tid] + gh[400 + tid]);
    float n = tanhf(dbi[800 + tid] + r * gh[800 + tid]);
    hid2[tid] = (1.f - z) * n + z * hid[tid];
  }
  __syncthreads();
  if (tid < 200) {
    float a = 0.f;
    for (int k = 0; k < 400; ++k) a += w2[(size_t)tid * 400 + k] * hid2[k];
    d2out[200 + tid] = a;
  }
}

// ---------------- fused logits + log_softmax: one block per batch ----------------
__global__ __launch_bounds__(512) void logits_lsm(
    const float* __restrict__ encw1, const float* __restrict__ d2,
    const float* __restrict__ vt, float* __restrict__ outp, int T) {
  int b = blockIdx.x;
  __shared__ float lg[2][512];
  __shared__ float red[512];
  const int tid = threadIdx.x;
  const int wave = tid >> 6, lane = tid & 63;
  for (int r = wave; r < T; r += 8) {
    const float* e = encw1 + ((size_t)b * T + r) * 200;
    float s0 = 0.f, s1 = 0.f;
    for (int p = lane; p < 200; p += 64) {
      float ev = e[p], v = vt[p];
      s0 += tanhf(ev + d2[p]) * v;
      s1 += tanhf(ev + d2[200 + p]) * v;
    }
    for (int off = 32; off; off >>= 1) {
      s0 += __shfl_down(s0, off);
      s1 += __shfl_down(s1, off);
    }
    if (lane == 0) { lg[0][r] = s0; lg[1][r] = s1; }
  }
  __syncthreads();
  for (int it = 0; it < 2; ++it) {
    red[tid] = lg[it][tid];
    __syncthreads();
    for (int s = 256; s; s >>= 1) {
      if (tid < s) red[tid] = fmaxf(red[tid], red[tid + s]);
      __syncthreads();
    }
    float m = red[0];
    __syncthreads();
    red[tid] = __expf(lg[it][tid] - m);
    __syncthreads();
    for (int s = 256; s; s >>= 1) {
      if (tid < s) red[tid] += red[tid + s];
      __syncthreads();
    }
    float lse = m + __logf(red[0]);
    __syncthreads();
    outp[((size_t)b * 2 + it) * T + tid] = lg[it][tid] - lse;
  }
}

extern "C" void kernel_launch(void* const* d_in, const int* in_sizes, int n_in,
                              void* d_out, int out_size, void* d_ws, size_t ws_size,
                              hipStream_t stream) {
  (void)in_sizes; (void)n_in; (void)out_size; (void)ws_size;
  const int B = 32, T = 512, L = 64;
  const int BT = B * T;
  const int BL = B * L;

  const int* x_word = (const int*)d_in[0];
  const int* x_query = (const int*)d_in[1];
  const float* embed = (const float*)d_in[2];
  const float* ctx_wi = (const float*)d_in[3];
  const float* ctx_wh = (const float*)d_in[4];
  const float* ctx_bi = (const float*)d_in[5];
  const float* ctx_bh = (const float*)d_in[6];
  const float* mod0_wi = (const float*)d_in[7];
  const float* mod0_wh = (const float*)d_in[8];
  const float* mod0_bi = (const float*)d_in[9];
  const float* mod0_bh = (const float*)d_in[10];
  const float* mod1_wi = (const float*)d_in[11];
  const float* mod1_wh = (const float*)d_in[12];
  const float* mod1_bi = (const float*)d_in[13];
  const float* mod1_bh = (const float*)d_in[14];
  const float* w_sim = (const float*)d_in[15];
  const float* enc_wi = (const float*)d_in[16];
  const float* enc_wh = (const float*)d_in[17];
  const float* enc_bi = (const float*)d_in[18];
  const float* enc_bh = (const float*)d_in[19];
  const float* dec_wh = (const float*)d_in[21];
  const float* dec_bi = (const float*)d_in[22];
  const float* dec_bh = (const float*)d_in[23];
  const float* w1 = (const float*)d_in[24];
  const float* w2 = (const float*)d_in[25];
  const float* vt = (const float*)d_in[26];
  float* out_f = (float*)d_out;

  char* ws = (char*)d_ws;
  size_t off = 0;
  auto alloc = [&](size_t bytes) -> void* {
    void* p = ws + off;
    off += (bytes + 255) & ~(size_t)255;
    return p;
  };
  u64* hx = (u64*)alloc((size_t)B * 2 * 400 * 8);
  bf16* ctx_wibf = (bf16*)alloc((size_t)60000 * 2);
  bf16* mod0_wibf = (bf16*)alloc((size_t)480000 * 2);
  bf16* mod1_wibf = (bf16*)alloc((size_t)120000 * 2);
  bf16* enc_wibf = (bf16*)alloc((size_t)240000 * 2);
  bf16* w1bf = (bf16*)alloc((size_t)80000 * 2);
  char* RA = (char*)alloc((size_t)BT * 1200 * 2);  // xw [BT,600] or xwe [BT,1200]
  bf16* xwFB = (bf16*)RA;
  bf16* xwe = (bf16*)RA;
  bf16* xwq = (bf16*)alloc((size_t)BL * 600 * 2);
  char* RB = (char*)alloc((size_t)BT * 800 * 2);
  bf16* G = (bf16*)RB;
  bf16* enc_outbf = (bf16*)RB;
  char* RC = (char*)alloc((size_t)2 * BT * 200 * 4);
  float* h_cat = (float*)RC;
  float* c2q = (float*)(RC + (size_t)BT * 200 * 4);
  bf16* M0bf = (bf16*)c2q;
  bf16* Mxbf = (bf16*)h_cat;
  float* encw1 = c2q;
  float* u_cat = (float*)alloc((size_t)BL * 200 * 4);
  float* smaxb = (float*)alloc((size_t)BT * 4);
  float* q2cb = (float*)alloc((size_t)B * 200 * 4);
  float* d2 = (float*)alloc((size_t)400 * 4);

  // ---- 0. zero hx EVERY call (stale tags would satisfy polls across graph replays) ----
  hipMemsetAsync(hx, 0, (size_t)B * 2 * 400 * 8, stream);

  // ---- 1. weight conversions (fused) ----
  cvt_all<<<(980000 + 255) / 256, 256, 0, stream>>>(ctx_wi, ctx_wibf, mod0_wi, mod0_wibf,
                                                    mod1_wi, mod1_wibf, enc_wi, enc_wibf,
                                                    w1, w1bf);

  // ---- 2. ctx input projections, embedding gather FUSED into A-staging ----
  gemm_mfma<bf16, true, true><<<dim3(BT / 128, 5), 256, 0, stream>>>(
      nullptr, x_word, embed, ctx_wibf, ctx_bi, xwFB, BT, 600, 100);
  gemm_mfma<bf16, true, true><<<dim3(BL / 128, 5), 256, 0, stream>>>(
      nullptr, x_query, embed, ctx_wibf, ctx_bi, xwq, BL, 600, 100);

  // ---- 3. ctx scans: word (T=512) and query (L=64) merged into one launch ----
  gru_scan100_1b<float><<<dim3(B, 4), 256, 0, stream>>>(
      xwFB, xwq, ctx_wh, ctx_bh, h_cat, u_cat, T, L);

  // ---- 4. attention ----
  attn_main<<<dim3(B, T / 32), 256, 0, stream>>>(h_cat, u_cat, w_sim, c2q, smaxb, T);
  softmax_q2c<<<B, 256, 0, stream>>>(smaxb, h_cat, q2cb, T);
  build_G<<<(BT * 200 + 255) / 256, 256, 0, stream>>>(h_cat, c2q, q2cb, G, T);

  // ---- 5. mod0 ----
  gemm_mfma<bf16, true, false><<<dim3(BT / 128, 5), 256, 0, stream>>>(
      G, nullptr, nullptr, mod0_wibf, mod0_bi, xwFB, BT, 600, 800);
  gru_scan100_1b<bf16><<<dim3(B, 2), 256, 0, stream>>>(
      xwFB, nullptr, mod0_wh, mod0_bh, M0bf, nullptr, T, T);

  // ---- 6. mod1 ----
  gemm_mfma<bf16, true, false><<<dim3(BT / 128, 5), 256, 0, stream>>>(
      M0bf, nullptr, nullptr, mod1_wibf, mod1_bi, xwFB, BT, 600, 200);
  gru_scan100_1b<bf16><<<dim3(B, 2), 256, 0, stream>>>(
      xwFB, nullptr, mod1_wh, mod1_bh, Mxbf, nullptr, T, T);

  // ---- 7. encoder ----
  gemm_mfma<bf16, true, false><<<dim3(BT / 128, 10), 256, 0, stream>>>(
      Mxbf, nullptr, nullptr, enc_wibf, enc_bi, xwe, BT, 1200, 200);
  gru_scan_enc_1b<<<dim3(B, 8), 448, 0, stream>>>(xwe, enc_wh, enc_bh, enc_outbf, hx, T);
  gemm_mfma<float, false, false><<<dim3(BT / 128, 2), 256, 0, stream>>>(
      enc_outbf, nullptr, nullptr, w1bf, nullptr, encw1, BT, 200, 400);

  // ---- 8. pointer decoder (fused logits + log_softmax) ----
  decoder_small<<<1, 512, 0, stream>>>(dec_wh, dec_bi, dec_bh, w2, d2);
  logits_lsm<<<B, 512, 0, stream>>>(encw1, d2, vt, out_f, T);
}